// Round 8
// baseline (11446.272 us; speedup 1.0000x reference)
//
#include <hip/hip_runtime.h>
#include <math.h>

#define TPB 512
#define NWG 256   // 32 groups x 8 WGs, 1 WG/CU
// GLOBAL phase barrier: all 256 WGs phase-lock. Same-slice WGs (32 per XCD)
// then stream the same ~0.5-1MB per-phase weight sub-slice in the same time
// window -> it L2-fits and one fill serves 32 readers.
// Arrive uses RELEASE, spin uses ACQUIRE (architectural ordering, not just a
// compiler fence) — closes the visibility hole suspected in rounds 5/7.

__device__ __forceinline__ float g_ld(const float* p){
    return __hip_atomic_load(p, __ATOMIC_RELAXED, __HIP_MEMORY_SCOPE_AGENT);
}
__device__ __forceinline__ void g_st(float* p, float v){
    __hip_atomic_store(p, v, __ATOMIC_RELAXED, __HIP_MEMORY_SCOPE_AGENT);
}
__device__ __forceinline__ float sigm(float x){ return 1.f/(1.f+expf(-x)); }

__global__ __launch_bounds__(TPB, 4) void decoder_persistent(
    const float* __restrict__ xs_h, const float* __restrict__ ys_e,
    const float* __restrict__ xs_mask, const float* __restrict__ ys_mask,
    const float* __restrict__ W_sinit, const float* __restrict__ b_sinit,
    const float* __restrict__ W_keys,
    const float* __restrict__ Wx_cell, const float* __restrict__ bx_cell,
    const float* __restrict__ gx_cell, const float* __restrict__ Wh_cell,
    const float* __restrict__ gh_cell,
    const float* __restrict__ Wx_cond, const float* __restrict__ bx_cond,
    const float* __restrict__ gx_cond, const float* __restrict__ Wh_cond,
    const float* __restrict__ gh_cond,
    const float* __restrict__ Wq, const float* __restrict__ bq,
    const float* __restrict__ V_att, const float* __restrict__ Wo,
    const float* __restrict__ bo, const float* __restrict__ Wy,
    const float* __restrict__ by, const float* __restrict__ Wc,
    const float* __restrict__ bc, const float* __restrict__ Wsm,
    const float* __restrict__ bs,
    float* __restrict__ out, float* __restrict__ ws)
{
    const int w    = blockIdx.x;
    const int tid  = threadIdx.x;
    const int lane = tid & 63, wv = tid >> 6;
    const int i    = w & 7;          // column slice (== XCD under %8 mapping; perf-only)
    const int grp  = w >> 3;         // group 0..31
    const int b0   = grp * 2;        // this group's 2 batch rows

    // ---------------- workspace layout (floats), total ~11.08M = 44.3 MB ----------------
    unsigned* cntg = (unsigned*)ws;                      // ONE global barrier ctr
    float* AXn  = ws + 1024;                             // [64][64][1536] LN'd x-branch
    float* uhP  = AXn  + (size_t)64*64*1536;             // [256][16][512] WG-private
    float* YWbP = uhP  + (size_t)256*16*512;             // [256][2][64][64] WG-private
    float* PB   = YWbP + (size_t)256*2*64*64;            // [32][18432] per-group block
    float* pb     = PB + (size_t)grp * 18432;
    float* tmpH_  = pb;            // [2][1536]
    float* tmpHC_ = pb + 3072;     // [2][1536]
    float* tmpXC_ = pb + 6144;     // [2][1536]
    float* qb_    = pb + 9216;     // [2][512]
    float* e_     = pb + 10240;    // [2][64][8]
    float* ctx0_  = pb + 11264;    // [2][1024]
    float* ctx_   = pb + 13312;    // [2][1024]
    float* pool_  = pb + 15360;    // [2][1024]
    float* s0_    = pb + 17408;    // [2][512]

    // ---------------- LDS (~62 KB) ----------------
    __shared__ float sal[2][512];    // carry s_t (identical in all 8 WGs)
    __shared__ float sbl[2][512];    // cell-GRU "state"
    __shared__ float al[2][64];      // alpha for head i
    __shared__ float outcl[2][64];   // ctx@Wc slice
    __shared__ float xml[2][64];     // xs_mask rows
    __shared__ float red[8][24];
    __shared__ float red2[24];
    __shared__ float arena[13056];   // staging + combine scratch
    float* xv   = arena;             // [2][1024] staging
    float* comb = arena + 2048;      // combine region (<= 4608 floats)

    unsigned gen = 0;
    auto gbar = [&](){
        __syncthreads();             // vmcnt(0) drain of this WG's g_st's
        ++gen;
        if (tid == 0){
            __hip_atomic_fetch_add(cntg, 1u, __ATOMIC_RELEASE, __HIP_MEMORY_SCOPE_AGENT);
            while (__hip_atomic_load(cntg, __ATOMIC_ACQUIRE, __HIP_MEMORY_SCOPE_AGENT) < 256u*gen)
                __builtin_amdgcn_s_sleep(2);
        }
        asm volatile("" ::: "memory");
        __syncthreads();
    };

    auto breduce = [&](float* v, int nv){
        for (int n = 0; n < nv; ++n){
            float x = v[n];
            #pragma unroll
            for (int o = 32; o; o >>= 1) x += __shfl_xor(x, o);
            v[n] = x;
        }
        if (lane == 0) for (int n = 0; n < nv; ++n) red[wv][n] = v[n];
        __syncthreads();
        if (tid < nv){ float s = 0.f; for (int q = 0; q < 8; ++q) s += red[q][tid]; red2[tid] = s; }
        __syncthreads();
        for (int n = 0; n < nv; ++n) v[n] = red2[n];
    };

    // dual-matrix sliced GEMV for 2 batch rows, 256 output cols, K-split 8.
    auto gemv2 = [&](const float* Wa, int lda, int ca,
                     const float* Wb, int ldb, int cb, int CGA,
                     const float* x0, const float* x1, int K)->float{
        int cg = tid & 63, kq = tid >> 6;
        const float* W; int ld, col;
        if (cg < CGA){ W = Wa; ld = lda; col = ca + 4*cg; }
        else         { W = Wb; ld = ldb; col = cb + 4*(cg - CGA); }
        int Kq = K >> 3;
        const float* wp = W + (size_t)(kq*Kq)*ld + col;
        const float* xa = x0 + kq*Kq;
        const float* xb = x1 + kq*Kq;
        float a0=0,a1=0,a2=0,a3=0, c0=0,c1=0,c2=0,c3=0;
        for (int kk = 0; kk < Kq; kk += 8){
            float4 wr[8];
            #pragma unroll
            for (int u = 0; u < 8; ++u) wr[u] = *(const float4*)(wp + (size_t)(kk+u)*ld);
            #pragma unroll
            for (int u = 0; u < 8; ++u){
                float xA = xa[kk+u], xB = xb[kk+u];
                a0 = fmaf(xA, wr[u].x, a0); a1 = fmaf(xA, wr[u].y, a1);
                a2 = fmaf(xA, wr[u].z, a2); a3 = fmaf(xA, wr[u].w, a3);
                c0 = fmaf(xB, wr[u].x, c0); c1 = fmaf(xB, wr[u].y, c1);
                c2 = fmaf(xB, wr[u].z, c2); c3 = fmaf(xB, wr[u].w, c3);
            }
        }
        float* cp = comb + tid*9;
        cp[0]=a0; cp[1]=a1; cp[2]=a2; cp[3]=a3;
        cp[4]=c0; cp[5]=c1; cp[6]=c2; cp[7]=c3;
        __syncthreads();
        int bb = tid >> 8, c = tid & 255, cgq = c >> 2, j = c & 3;
        float s = 0.f;
        #pragma unroll
        for (int q = 0; q < 8; ++q) s += comb[(q*64 + cgq)*9 + bb*4 + j];
        __syncthreads();
        return s;
    };

    // ======================= precompute =======================
    if (tid < 128) xml[tid>>6][tid&63] = xs_mask[(size_t)(b0 + (tid>>6))*64 + (tid&63)];
    __syncthreads();

    // ---- uh (private): 16 jobs (2b x 8 l), 512 cols, K=1024; W_keys read once ----
    {
        int c4 = tid & 127, kq = tid >> 7;           // 4 kq x 256 k
        unsigned base[16];
        #pragma unroll
        for (int j = 0; j < 16; ++j){
            int bb = j >> 3, l = i*8 + (j & 7);
            base[j] = (unsigned)(((b0+bb)*64 + l)*1024 + kq*256);
        }
        const float* wp = W_keys + (size_t)(kq*256)*512 + 4*c4;
        float4 acc[16];
        #pragma unroll
        for (int j = 0; j < 16; ++j) acc[j] = make_float4(0.f,0.f,0.f,0.f);
        for (int kk = 0; kk < 256; ++kk){
            float4 wr = *(const float4*)(wp + (size_t)kk*512);
            #pragma unroll
            for (int j = 0; j < 16; ++j){
                float xr = xs_h[base[j] + kk];
                acc[j].x = fmaf(xr, wr.x, acc[j].x); acc[j].y = fmaf(xr, wr.y, acc[j].y);
                acc[j].z = fmaf(xr, wr.z, acc[j].z); acc[j].w = fmaf(xr, wr.w, acc[j].w);
            }
        }
        for (int r = 0; r < 16; ++r){
            float* cp = arena + tid*5;
            cp[0]=acc[r].x; cp[1]=acc[r].y; cp[2]=acc[r].z; cp[3]=acc[r].w;
            __syncthreads();
            int c = tid; float s = 0.f;
            #pragma unroll
            for (int q = 0; q < 4; ++q) s += arena[(q*128 + (c>>2))*5 + (c&3)];
            uhP[((size_t)w*16 + r)*512 + c] = s;
            __syncthreads();
        }
    }

    // ---- AXn (published to group): 16 rows (2b x 8 t), LN(ys_e@Wx_cell)*gx+bx ----
    // TWO-PASS LN variance (round-3 lesson).
    for (int g = 0; g < 3; ++g){
        int c4 = tid & 127, kq = tid >> 7;           // 4 kq x 128 k
        unsigned base[16];
        #pragma unroll
        for (int j = 0; j < 16; ++j){
            int bb = j >> 3, t = i*8 + (j & 7);
            base[j] = (unsigned)(((b0+bb)*64 + t)*512 + kq*128);
        }
        const float* wp = Wx_cell + (size_t)(kq*128)*1536 + g*512 + 4*c4;
        float4 acc[16];
        #pragma unroll
        for (int j = 0; j < 16; ++j) acc[j] = make_float4(0.f,0.f,0.f,0.f);
        for (int kk = 0; kk < 128; ++kk){
            float4 wr = *(const float4*)(wp + (size_t)kk*1536);
            #pragma unroll
            for (int j = 0; j < 16; ++j){
                float xr = ys_e[base[j] + kk];
                acc[j].x = fmaf(xr, wr.x, acc[j].x); acc[j].y = fmaf(xr, wr.y, acc[j].y);
                acc[j].z = fmaf(xr, wr.z, acc[j].z); acc[j].w = fmaf(xr, wr.w, acc[j].w);
            }
        }
        for (int r = 0; r < 16; ++r){
            float* cp = arena + tid*5;
            cp[0]=acc[r].x; cp[1]=acc[r].y; cp[2]=acc[r].z; cp[3]=acc[r].w;
            __syncthreads();
            int c = tid; float val = 0.f;
            #pragma unroll
            for (int q = 0; q < 4; ++q) val += arena[(q*128 + (c>>2))*5 + (c&3)];
            float s1[1] = { val };
            breduce(s1, 1);
            float mu = s1[0]*(1.f/512.f);
            float d = val - mu;
            float s2[1] = { d*d };
            breduce(s2, 1);
            float rstd = rsqrtf(s2[0]*(1.f/512.f) + 1e-5f);
            int bb = r >> 3, t = i*8 + (r & 7), cg2 = g*512 + c;
            g_st(&AXn[(((size_t)(b0+bb))*64 + t)*1536 + cg2],
                 d*rstd*gx_cell[cg2] + bx_cell[cg2]);
            __syncthreads();
        }
    }

    // ---- YWb (private): 128 rows (2b x 64 t) in 8 chunks, 64-col slice ----
    for (int cc = 0; cc < 8; ++cc){
        int c4 = tid & 15, kq = tid >> 4;            // 32 kq x 16 k
        unsigned base[16];
        #pragma unroll
        for (int r = 0; r < 16; ++r){
            int rg = cc*16 + r, bb = rg >> 6, t = rg & 63;
            base[r] = (unsigned)(((b0+bb)*64 + t)*512 + kq*16);
        }
        const float* wp = Wy + (size_t)(kq*16)*512 + i*64 + 4*c4;
        float4 acc[16];
        #pragma unroll
        for (int r = 0; r < 16; ++r) acc[r] = make_float4(0.f,0.f,0.f,0.f);
        for (int kk = 0; kk < 16; ++kk){
            float4 wr = *(const float4*)(wp + (size_t)kk*512);
            #pragma unroll
            for (int r = 0; r < 16; ++r){
                float xr = ys_e[base[r] + kk];
                acc[r].x = fmaf(xr, wr.x, acc[r].x); acc[r].y = fmaf(xr, wr.y, acc[r].y);
                acc[r].z = fmaf(xr, wr.z, acc[r].z); acc[r].w = fmaf(xr, wr.w, acc[r].w);
            }
        }
        for (int r = 0; r < 16; ++r){
            float* cp = arena + tid*5;
            cp[0]=acc[r].x; cp[1]=acc[r].y; cp[2]=acc[r].z; cp[3]=acc[r].w;
            __syncthreads();
            if (tid < 64){
                int c = tid; float s = 0.f;
                #pragma unroll
                for (int q = 0; q < 32; ++q) s += arena[(q*16 + (c>>2))*5 + (c&3)];
                int rg = cc*16 + r, bb = rg >> 6, t = rg & 63;
                YWbP[(((size_t)w*2 + bb)*64 + t)*64 + c] = s + by[i*64 + c];
            }
            __syncthreads();
        }
    }

    // ---- pooled slice ----
    if (tid < 256){
        int bb = tid >> 7, c = i*128 + (tid & 127);
        float msum = 0.f;
        for (int l = 0; l < 64; ++l) msum += xml[bb][l];
        float a = 0.f;
        for (int l = 0; l < 64; ++l)
            a += xs_h[((size_t)(b0+bb)*64 + l)*1024 + c] * xml[bb][l];
        g_st(&pool_[bb*1024 + c], a / msum);
    }
    gbar();   // publish AXn + pooled

    // ---- s0 = tanh(pooled @ W_sinit + b) ----
    for (int k = tid; k < 2048; k += TPB) xv[k] = g_ld(&pool_[k]);
    __syncthreads();
    {
        int c4 = tid & 15, kq = tid >> 4;            // 32 kq x 32 k
        const float* wp = W_sinit + (size_t)(kq*32)*512 + i*64 + 4*c4;
        float4 A = make_float4(0.f,0.f,0.f,0.f), Bv = make_float4(0.f,0.f,0.f,0.f);
        for (int kk = 0; kk < 32; ++kk){
            float4 wr = *(const float4*)(wp + (size_t)kk*512);
            float xA = xv[kq*32 + kk], xB = xv[1024 + kq*32 + kk];
            A.x = fmaf(xA, wr.x, A.x); A.y = fmaf(xA, wr.y, A.y);
            A.z = fmaf(xA, wr.z, A.z); A.w = fmaf(xA, wr.w, A.w);
            Bv.x = fmaf(xB, wr.x, Bv.x); Bv.y = fmaf(xB, wr.y, Bv.y);
            Bv.z = fmaf(xB, wr.z, Bv.z); Bv.w = fmaf(xB, wr.w, Bv.w);
        }
        float* cp = comb + tid*9;
        cp[0]=A.x; cp[1]=A.y; cp[2]=A.z; cp[3]=A.w;
        cp[4]=Bv.x; cp[5]=Bv.y; cp[6]=Bv.z; cp[7]=Bv.w;
        __syncthreads();
        if (tid < 128){
            int bb = tid >> 6, c = tid & 63; float s = 0.f;
            #pragma unroll
            for (int q = 0; q < 32; ++q) s += comb[(q*16 + (c>>2))*9 + bb*4 + (c&3)];
            g_st(&s0_[bb*512 + i*64 + c], tanhf(s + b_sinit[i*64 + c]));
        }
        __syncthreads();
    }
    gbar();
    sal[0][tid] = g_ld(&s0_[tid]);
    sal[1][tid] = g_ld(&s0_[512 + tid]);
    __syncthreads();

    // ---- tmpH for t=0 ----
    {
        float r0 = gemv2(Wsm, 512, i*64, Wh_cell, 1536, i*192, 16,
                         &sal[0][0], &sal[1][0], 512);
        int bb = tid >> 8, c = tid & 255;
        if (c >= 64) g_st(&tmpH_[bb*1536 + i*192 + (c - 64)], r0);
    }
    gbar();

    // ======================= sequential scan =======================
    for (int t = 0; t < 64; ++t){
        float ymr[2] = { ys_mask[(size_t)b0*64 + t], ys_mask[(size_t)(b0+1)*64 + t] };

        // ---- phase A: cell-GRU (redundant, two-pass LN) + qb/tmpHC slice ----
        {
            float th[2][3], ax[2][3], st[6];
            #pragma unroll
            for (int bb = 0; bb < 2; ++bb)
                #pragma unroll
                for (int g = 0; g < 3; ++g){
                    th[bb][g] = g_ld(&tmpH_[bb*1536 + g*512 + tid]);
                    ax[bb][g] = g_ld(&AXn[(((size_t)(b0+bb))*64 + t)*1536 + g*512 + tid]);
                    st[bb*3+g] = th[bb][g];
                }
            breduce(st, 6);
            float dv[2][3], st2[6];
            #pragma unroll
            for (int bb = 0; bb < 2; ++bb)
                #pragma unroll
                for (int g = 0; g < 3; ++g){
                    float mu = st[bb*3+g]*(1.f/512.f);
                    dv[bb][g] = th[bb][g] - mu;
                    st2[bb*3+g] = dv[bb][g]*dv[bb][g];
                }
            breduce(st2, 6);
            #pragma unroll
            for (int bb = 0; bb < 2; ++bb){
                float ah[3];
                #pragma unroll
                for (int g = 0; g < 3; ++g){
                    float var = st2[bb*3+g]*(1.f/512.f);
                    ah[g] = dv[bb][g]*rsqrtf(var + 1e-5f)*gh_cell[g*512 + tid];
                }
                float h  = sal[bb][tid];
                float r  = sigm(ax[bb][0] + ah[0]);
                float z  = sigm(ax[bb][1] + ah[1]);
                float hc = tanhf(ax[bb][2] + r*ah[2]);
                float hn = (1.f - z)*h + z*hc;
                sbl[bb][tid] = ymr[bb]*hn + (1.f - ymr[bb])*h;
            }
        }
        __syncthreads();
        {
            float ra = gemv2(Wq, 512, i*64, Wh_cond, 1536, i*192, 16,
                             &sbl[0][0], &sbl[1][0], 512);
            int bb = tid >> 8, c = tid & 255;
            if (c < 64){ int col = i*64 + c; g_st(&qb_[bb*512 + col], ra + bq[col]); }
            else g_st(&tmpHC_[bb*1536 + i*192 + (c - 64)], ra);
        }
        gbar();  // A

        // ---- phase B: attention scores for my 16 (b,l) jobs ----
        for (int k = tid; k < 1024; k += TPB) xv[k] = g_ld(&qb_[k]);
        __syncthreads();
        for (int jj = wv; jj < 16; jj += 8){
            int bb = jj >> 3, l = i*8 + (jj & 7);
            float acc[8] = {0.f,0.f,0.f,0.f,0.f,0.f,0.f,0.f};
            #pragma unroll
            for (int u = 0; u < 8; ++u){
                int d = u*64 + lane;
                float hid = tanhf(uhP[((size_t)w*16 + jj)*512 + d] + xv[bb*512 + d]);
                float4 va = *(const float4*)&V_att[(size_t)d*8];
                float4 vb = *(const float4*)&V_att[(size_t)d*8 + 4];
                acc[0] = fmaf(hid, va.x, acc[0]); acc[1] = fmaf(hid, va.y, acc[1]);
                acc[2] = fmaf(hid, va.z, acc[2]); acc[3] = fmaf(hid, va.w, acc[3]);
                acc[4] = fmaf(hid, vb.x, acc[4]); acc[5] = fmaf(hid, vb.y, acc[5]);
                acc[6] = fmaf(hid, vb.z, acc[6]); acc[7] = fmaf(hid, vb.w, acc[7]);
            }
            #pragma unroll
            for (int h = 0; h < 8; ++h)
                #pragma unroll
                for (int o = 32; o; o >>= 1) acc[h] += __shfl_xor(acc[h], o);
            if (lane == 0){
                float mk = xml[bb][l];
                #pragma unroll
                for (int h = 0; h < 8; ++h)
                    g_st(&e_[((size_t)bb*64 + l)*8 + h], (mk > 0.f) ? acc[h] : -1e9f);
            }
        }
        gbar();  // B

        // ---- phase C: softmax (head i) + ctx0 slice ----
        if (wv < 2){
            int bb = wv;
            float v = g_ld(&e_[((size_t)bb*64 + lane)*8 + i]);
            float mx = v;
            #pragma unroll
            for (int o = 32; o; o >>= 1) mx = fmaxf(mx, __shfl_xor(mx, o));
            float ex = expf(v - mx);
            float ss = ex;
            #pragma unroll
            for (int o = 32; o; o >>= 1) ss += __shfl_xor(ss, o);
            al[bb][lane] = ex / ss;
        }
        __syncthreads();
        {
            int kq = tid >> 6, job = tid & 63, bb = job >> 5, cg = job & 31;
            int c0 = i*128 + 4*cg;
            float4 a4 = make_float4(0.f,0.f,0.f,0.f);
            #pragma unroll
            for (int u = 0; u < 8; ++u){
                int l = kq*8 + u;
                float a = al[bb][l];
                float4 xw = *(const float4*)&xs_h[((size_t)(b0+bb)*64 + l)*1024 + c0];
                a4.x = fmaf(a, xw.x, a4.x); a4.y = fmaf(a, xw.y, a4.y);
                a4.z = fmaf(a, xw.z, a4.z); a4.w = fmaf(a, xw.w, a4.w);
            }
            float* cp = comb + tid*5;
            cp[0]=a4.x; cp[1]=a4.y; cp[2]=a4.z; cp[3]=a4.w;
            __syncthreads();
            if (tid < 256){
                int bb2 = tid >> 7, c = tid & 127; float s = 0.f;
                #pragma unroll
                for (int q = 0; q < 8; ++q) s += comb[(q*64 + bb2*32 + (c>>2))*5 + (c&3)];
                g_st(&ctx0_[bb2*1024 + i*128 + c], s);
            }
            __syncthreads();
        }
        gbar();  // C

        // ---- phase D: ctx = (ctx0 @ Wo + bo) * ym  (direct Wo, K-split 16) ----
        for (int k = tid; k < 2048; k += TPB) xv[k] = g_ld(&ctx0_[k]);
        __syncthreads();
        {
            int kq = tid >> 5, cg = tid & 31;        // 16 kq x 64 k, 32 cg x 4 cols
            int c0 = i*128 + 4*cg;
            const float* wp = Wo + (size_t)(kq*64)*1024 + c0;
            const float* xa = xv + kq*64;
            const float* xb = xv + 1024 + kq*64;
            float a0=0,a1=0,a2=0,a3=0, d0=0,d1=0,d2=0,d3=0;
            for (int kk = 0; kk < 64; kk += 8){
                float4 wr[8];
                #pragma unroll
                for (int u = 0; u < 8; ++u) wr[u] = *(const float4*)(wp + (size_t)(kk+u)*1024);
                #pragma unroll
                for (int u = 0; u < 8; ++u){
                    float xA = xa[kk+u], xB = xb[kk+u];
                    a0 = fmaf(xA, wr[u].x, a0); a1 = fmaf(xA, wr[u].y, a1);
                    a2 = fmaf(xA, wr[u].z, a2); a3 = fmaf(xA, wr[u].w, a3);
                    d0 = fmaf(xB, wr[u].x, d0); d1 = fmaf(xB, wr[u].y, d1);
                    d2 = fmaf(xB, wr[u].z, d2); d3 = fmaf(xB, wr[u].w, d3);
                }
            }
            float* cp = comb + tid*9;
            cp[0]=a0; cp[1]=a1; cp[2]=a2; cp[3]=a3;
            cp[4]=d0; cp[5]=d1; cp[6]=d2; cp[7]=d3;
            __syncthreads();
            if (tid < 256){
                int bb2 = tid >> 7, c = tid & 127; float s = 0.f;
                #pragma unroll
                for (int q = 0; q < 16; ++q) s += comb[(q*32 + (c>>2))*9 + bb2*4 + (c&3)];
                float ym2 = bb2 ? ymr[1] : ymr[0];
                g_st(&ctx_[bb2*1024 + i*128 + c], (s + bo[i*128 + c]) * ym2);
            }
            __syncthreads();
        }
        gbar();  // D

        // ---- phase E: tmpXC (Wx_cond) + outc (Wc) from ctx ----
        for (int k = tid; k < 2048; k += TPB) xv[k] = g_ld(&ctx_[k]);
        __syncthreads();
        {
            float re = gemv2(Wx_cond, 1536, i*192, Wc, 512, i*64, 48,
                             &xv[0], &xv[1024], 1024);
            int bb = tid >> 8, c = tid & 255;
            if (c < 192){
                g_st(&tmpXC_[bb*1536 + i*192 + c], re);
            } else {
                outcl[bb][c - 192] = re;
            }
        }
        gbar();  // E

        // ---- phase F: cond-GRU (redundant, two-pass LN) + out + tmpH(t+1) ----
        {
            float tx[2][3], th[2][3], st[12];
            #pragma unroll
            for (int bb = 0; bb < 2; ++bb)
                #pragma unroll
                for (int g = 0; g < 3; ++g){
                    tx[bb][g] = g_ld(&tmpXC_[bb*1536 + g*512 + tid]);
                    th[bb][g] = g_ld(&tmpHC_[bb*1536 + g*512 + tid]);
                    st[bb*3+g]     = tx[bb][g];
                    st[6 + bb*3+g] = th[bb][g];
                }
            breduce(st, 12);
            float dx[2][3], dh[2][3], st2[12];
            #pragma unroll
            for (int bb = 0; bb < 2; ++bb)
                #pragma unroll
                for (int g = 0; g < 3; ++g){
                    float mux = st[bb*3+g]*(1.f/512.f);
                    float muh = st[6 + bb*3+g]*(1.f/512.f);
                    dx[bb][g] = tx[bb][g] - mux;
                    dh[bb][g] = th[bb][g] - muh;
                    st2[bb*3+g]     = dx[bb][g]*dx[bb][g];
                    st2[6 + bb*3+g] = dh[bb][g]*dh[bb][g];
                }
            breduce(st2, 12);
            float snew[2];
            #pragma unroll
            for (int bb = 0; bb < 2; ++bb){
                float axc[3], ahc[3];
                #pragma unroll
                for (int g = 0; g < 3; ++g){
                    int c2 = g*512 + tid;
                    float vax = st2[bb*3+g]*(1.f/512.f);
                    float vah = st2[6 + bb*3+g]*(1.f/512.f);
                    axc[g] = dx[bb][g]*rsqrtf(vax + 1e-5f)*gx_cond[c2] + bx_cond[c2];
                    ahc[g] = dh[bb][g]*rsqrtf(vah + 1e-5f)*gh_cond[c2];
                }
                float h  = sbl[bb][tid];
                float r  = sigm(axc[0] + ahc[0]);
                float z  = sigm(axc[1] + ahc[1]);
                float hc = tanhf(axc[2] + r*ahc[2]);
                float hn = (1.f - z)*h + z*hc;
                snew[bb] = ymr[bb]*hn + (1.f - ymr[bb])*h;
            }
            sal[0][tid] = snew[0];
            sal[1][tid] = snew[1];
        }
        __syncthreads();
        {
            float rf = gemv2(Wsm, 512, i*64, Wh_cell, 1536, i*192, 16,
                             &sal[0][0], &sal[1][0], 512);
            int bb = tid >> 8, c = tid & 255;
            if (c < 64){
                int col = i*64 + c;
                float ymf = bb ? ymr[1] : ymr[0];
                float v = rf + YWbP[(((size_t)w*2 + bb)*64 + t)*64 + c]
                        + outcl[bb][c] + bc[col] + bs[col];
                out[(((size_t)(b0+bb))*64 + t)*512 + col] = tanhf(v)*ymf;
            } else {
                g_st(&tmpH_[bb*1536 + i*192 + (c - 64)], rf);
            }
        }
        gbar();  // F
    }
}

// ---------------------------------------------------------------------------
extern "C" void kernel_launch(void* const* d_in, const int* in_sizes, int n_in,
                              void* d_out, int out_size, void* d_ws, size_t ws_size,
                              hipStream_t stream)
{
    // re-zero the global barrier counter on every graph replay
    hipMemsetAsync(d_ws, 0, 4096, stream);

    decoder_persistent<<<dim3(NWG), dim3(TPB), 0, stream>>>(
        (const float*)d_in[0],  (const float*)d_in[1],  (const float*)d_in[2],
        (const float*)d_in[3],  (const float*)d_in[4],  (const float*)d_in[5],
        (const float*)d_in[6],  (const float*)d_in[7],  (const float*)d_in[8],
        (const float*)d_in[9],  (const float*)d_in[10], (const float*)d_in[11],
        (const float*)d_in[12], (const float*)d_in[13], (const float*)d_in[14],
        (const float*)d_in[15], (const float*)d_in[16], (const float*)d_in[17],
        (const float*)d_in[18], (const float*)d_in[19], (const float*)d_in[20],
        (const float*)d_in[21], (const float*)d_in[22], (const float*)d_in[23],
        (const float*)d_in[24], (const float*)d_in[25], (const float*)d_in[26],
        (const float*)d_in[27],
        (float*)d_out, (float*)d_ws);
}

// Round 9
// 9947.030 us; speedup vs baseline: 1.1507x; 1.1507x over previous
//
#include <hip/hip_runtime.h>
#include <math.h>

#define TPB 512
#define NWG 256   // 32 groups x 8 WGs, 1 WG/CU

// Cross-WG traffic: agent-scope atomics (coherence point, no stale-L2 reads).
// Barrier arrive = RELEASE, spin = ACQUIRE (round-8-proven protocol) at the
// cheap round-4 scale (8 arrivals per group).
__device__ __forceinline__ float g_ld(const float* p){
    return __hip_atomic_load(p, __ATOMIC_RELAXED, __HIP_MEMORY_SCOPE_AGENT);
}
__device__ __forceinline__ void g_st(float* p, float v){
    __hip_atomic_store(p, v, __ATOMIC_RELAXED, __HIP_MEMORY_SCOPE_AGENT);
}
__device__ __forceinline__ float sigm(float x){ return 1.f/(1.f+expf(-x)); }

__global__ __launch_bounds__(TPB, 2) void decoder_persistent(
    const float* __restrict__ xs_h, const float* __restrict__ ys_e,
    const float* __restrict__ xs_mask, const float* __restrict__ ys_mask,
    const float* __restrict__ W_sinit, const float* __restrict__ b_sinit,
    const float* __restrict__ W_keys,
    const float* __restrict__ Wx_cell, const float* __restrict__ bx_cell,
    const float* __restrict__ gx_cell, const float* __restrict__ Wh_cell,
    const float* __restrict__ gh_cell,
    const float* __restrict__ Wx_cond, const float* __restrict__ bx_cond,
    const float* __restrict__ gx_cond, const float* __restrict__ Wh_cond,
    const float* __restrict__ gh_cond,
    const float* __restrict__ Wq, const float* __restrict__ bq,
    const float* __restrict__ V_att, const float* __restrict__ Wo,
    const float* __restrict__ bo, const float* __restrict__ Wy,
    const float* __restrict__ by, const float* __restrict__ Wc,
    const float* __restrict__ bc, const float* __restrict__ Wsm,
    const float* __restrict__ bs,
    float* __restrict__ out, float* __restrict__ ws)
{
    const int w    = blockIdx.x;
    const int tid  = threadIdx.x;
    const int lane = tid & 63, wv = tid >> 6;
    const int i    = w & 7;          // column slice (== XCD under %8 mapping; perf-only)
    const int grp  = w >> 3;         // group 0..31
    const int b0   = grp * 2;        // this group's 2 batch rows

    // ---------------- workspace layout (floats), total ~11.08M = 44.3 MB ----------------
    unsigned* cntg = (unsigned*)ws + (size_t)grp * 16;   // group barrier ctr (64B padded)
    float* AXn  = ws + 1024;                             // [64][64][1536] LN'd x-branch
    float* uhP  = AXn  + (size_t)64*64*1536;             // [256][8192] WG-private, d-sliced uh
    float* YWbP = uhP  + (size_t)256*16*512;             // [256][2][64][64] WG-private
    float* PB   = YWbP + (size_t)256*2*64*64;            // [32][18432] per-group block
    float* pb     = PB + (size_t)grp * 18432;
    float* tmpH_  = pb;            // [2][1536]
    float* tmpHC_ = pb + 3072;     // [2][1536]
    float* tmpXC_ = pb + 6144;     // [2][1536]
    //                pb + 9216    // [2][512] (qb slot — unused now)
    float* e_     = pb + 10240;    // [2][64][8] atomically-accumulated scores
    float* ctx0_  = pb + 11264;    // [2][1024]
    float* ctx_   = pb + 13312;    // [2][1024]
    float* pool_  = pb + 15360;    // [2][1024]
    float* s0_    = pb + 17408;    // [2][512]

    float* uhT = uhP + (size_t)w * 8192;   // [128 jobs = (bb,l)][64 dd]

    // ---------------- LDS (~63 KB) ----------------
    __shared__ float sal[2][512];    // carry s_t (identical in all 8 WGs)
    __shared__ float sbl[2][512];    // cell-GRU "state"
    __shared__ float qbl[2][64];     // qb slice (cols i*64..), LOCAL only
    __shared__ float al[2][64];      // alpha for head i
    __shared__ float outcl[2][64];   // ctx@Wc slice
    __shared__ float xml[2][64];     // xs_mask rows
    __shared__ float red[8][24];
    __shared__ float red2[24];
    __shared__ float arena[13056];   // staging + combine scratch
    float* xv   = arena;             // [2][1024] staging
    float* comb = arena + 2048;      // combine region (<= 4608 floats)

    unsigned gen = 0;
    auto gbar = [&](){
        __syncthreads();             // vmcnt(0) drain of this WG's stores
        ++gen;
        if (tid == 0){
            __hip_atomic_fetch_add(cntg, 1u, __ATOMIC_RELEASE, __HIP_MEMORY_SCOPE_AGENT);
            while (__hip_atomic_load(cntg, __ATOMIC_ACQUIRE, __HIP_MEMORY_SCOPE_AGENT) < 8u*gen)
                __builtin_amdgcn_s_sleep(2);
        }
        asm volatile("" ::: "memory");
        __syncthreads();
    };

    auto breduce = [&](float* v, int nv){
        for (int n = 0; n < nv; ++n){
            float x = v[n];
            #pragma unroll
            for (int o = 32; o; o >>= 1) x += __shfl_xor(x, o);
            v[n] = x;
        }
        if (lane == 0) for (int n = 0; n < nv; ++n) red[wv][n] = v[n];
        __syncthreads();
        if (tid < nv){ float s = 0.f; for (int q = 0; q < 8; ++q) s += red[q][tid]; red2[tid] = s; }
        __syncthreads();
        for (int n = 0; n < nv; ++n) v[n] = red2[n];
    };

    // dual-matrix sliced GEMV for 2 batch rows, 256 output cols, K-split 8.
    // 16-deep load batches (same FMA order per accumulator as 8-deep).
    auto gemv2 = [&](const float* Wa, int lda, int ca,
                     const float* Wb, int ldb, int cb, int CGA,
                     const float* x0, const float* x1, int K)->float{
        int cg = tid & 63, kq = tid >> 6;
        const float* W; int ld, col;
        if (cg < CGA){ W = Wa; ld = lda; col = ca + 4*cg; }
        else         { W = Wb; ld = ldb; col = cb + 4*(cg - CGA); }
        int Kq = K >> 3;
        const float* wp = W + (size_t)(kq*Kq)*ld + col;
        const float* xa = x0 + kq*Kq;
        const float* xb = x1 + kq*Kq;
        float a0=0,a1=0,a2=0,a3=0, c0=0,c1=0,c2=0,c3=0;
        for (int kk = 0; kk < Kq; kk += 16){
            float4 wr[16];
            #pragma unroll
            for (int u = 0; u < 16; ++u) wr[u] = *(const float4*)(wp + (size_t)(kk+u)*ld);
            #pragma unroll
            for (int u = 0; u < 16; ++u){
                float xA = xa[kk+u], xB = xb[kk+u];
                a0 = fmaf(xA, wr[u].x, a0); a1 = fmaf(xA, wr[u].y, a1);
                a2 = fmaf(xA, wr[u].z, a2); a3 = fmaf(xA, wr[u].w, a3);
                c0 = fmaf(xB, wr[u].x, c0); c1 = fmaf(xB, wr[u].y, c1);
                c2 = fmaf(xB, wr[u].z, c2); c3 = fmaf(xB, wr[u].w, c3);
            }
        }
        float* cp = comb + tid*9;
        cp[0]=a0; cp[1]=a1; cp[2]=a2; cp[3]=a3;
        cp[4]=c0; cp[5]=c1; cp[6]=c2; cp[7]=c3;
        __syncthreads();
        int bb = tid >> 8, c = tid & 255, cgq = c >> 2, j = c & 3;
        float s = 0.f;
        #pragma unroll
        for (int q = 0; q < 8; ++q) s += comb[(q*64 + cgq)*9 + bb*4 + j];
        __syncthreads();
        return s;
    };

    // ======================= precompute =======================
    if (tid < 128) xml[tid>>6][tid&63] = xs_mask[(size_t)(b0 + (tid>>6))*64 + (tid&63)];
    // zero the atomic e-buffer (redundant across WGs; benign)
    for (int k = tid; k < 1024; k += TPB) g_st(&e_[k], 0.f);
    __syncthreads();

    // ---- uhT (private, d-sliced): uh[(bb,l), dd] for dd in my 64-col slice.
    // 8 chunks of 16 (bb,l) jobs; K=1024 split 32 ways; W_keys slice stays L2-hot.
    for (int cc = 0; cc < 8; ++cc){
        int c4 = tid & 15, kq = tid >> 4;            // 32 kq x 32 k
        unsigned base[16];
        #pragma unroll
        for (int r = 0; r < 16; ++r){
            int jg = cc*16 + r, bb = jg >> 6, l = jg & 63;
            base[r] = (unsigned)(((b0+bb)*64 + l)*1024 + kq*32);
        }
        const float* wp = W_keys + (size_t)(kq*32)*512 + i*64 + 4*c4;
        float4 acc[16];
        #pragma unroll
        for (int r = 0; r < 16; ++r) acc[r] = make_float4(0.f,0.f,0.f,0.f);
        for (int kk = 0; kk < 32; ++kk){
            float4 wr = *(const float4*)(wp + (size_t)kk*512);
            #pragma unroll
            for (int r = 0; r < 16; ++r){
                float xr = xs_h[base[r] + kk];
                acc[r].x = fmaf(xr, wr.x, acc[r].x); acc[r].y = fmaf(xr, wr.y, acc[r].y);
                acc[r].z = fmaf(xr, wr.z, acc[r].z); acc[r].w = fmaf(xr, wr.w, acc[r].w);
            }
        }
        for (int r = 0; r < 16; ++r){
            float* cp = arena + tid*5;
            cp[0]=acc[r].x; cp[1]=acc[r].y; cp[2]=acc[r].z; cp[3]=acc[r].w;
            __syncthreads();
            if (tid < 64){
                int c = tid; float s = 0.f;
                #pragma unroll
                for (int q = 0; q < 32; ++q) s += arena[(q*16 + (c>>2))*5 + (c&3)];
                uhT[(cc*16 + r)*64 + c] = s;
            }
            __syncthreads();
        }
    }

    // ---- AXn (published to group): 16 rows (2b x 8 t), LN(ys_e@Wx_cell)*gx+bx ----
    // TWO-PASS LN variance (round-3 lesson).
    for (int g = 0; g < 3; ++g){
        int c4 = tid & 127, kq = tid >> 7;           // 4 kq x 128 k
        unsigned base[16];
        #pragma unroll
        for (int j = 0; j < 16; ++j){
            int bb = j >> 3, t = i*8 + (j & 7);
            base[j] = (unsigned)(((b0+bb)*64 + t)*512 + kq*128);
        }
        const float* wp = Wx_cell + (size_t)(kq*128)*1536 + g*512 + 4*c4;
        float4 acc[16];
        #pragma unroll
        for (int j = 0; j < 16; ++j) acc[j] = make_float4(0.f,0.f,0.f,0.f);
        for (int kk = 0; kk < 128; ++kk){
            float4 wr = *(const float4*)(wp + (size_t)kk*1536);
            #pragma unroll
            for (int j = 0; j < 16; ++j){
                float xr = ys_e[base[j] + kk];
                acc[j].x = fmaf(xr, wr.x, acc[j].x); acc[j].y = fmaf(xr, wr.y, acc[j].y);
                acc[j].z = fmaf(xr, wr.z, acc[j].z); acc[j].w = fmaf(xr, wr.w, acc[j].w);
            }
        }
        for (int r = 0; r < 16; ++r){
            float* cp = arena + tid*5;
            cp[0]=acc[r].x; cp[1]=acc[r].y; cp[2]=acc[r].z; cp[3]=acc[r].w;
            __syncthreads();
            int c = tid; float val = 0.f;
            #pragma unroll
            for (int q = 0; q < 4; ++q) val += arena[(q*128 + (c>>2))*5 + (c&3)];
            float s1[1] = { val };
            breduce(s1, 1);
            float mu = s1[0]*(1.f/512.f);
            float d = val - mu;
            float s2[1] = { d*d };
            breduce(s2, 1);
            float rstd = rsqrtf(s2[0]*(1.f/512.f) + 1e-5f);
            int bb = r >> 3, t = i*8 + (r & 7), cg2 = g*512 + c;
            g_st(&AXn[(((size_t)(b0+bb))*64 + t)*1536 + cg2],
                 d*rstd*gx_cell[cg2] + bx_cell[cg2]);
            __syncthreads();
        }
    }

    // ---- YWb (private): 128 rows (2b x 64 t) in 8 chunks, 64-col slice ----
    for (int cc = 0; cc < 8; ++cc){
        int c4 = tid & 15, kq = tid >> 4;            // 32 kq x 16 k
        unsigned base[16];
        #pragma unroll
        for (int r = 0; r < 16; ++r){
            int rg = cc*16 + r, bb = rg >> 6, t = rg & 63;
            base[r] = (unsigned)(((b0+bb)*64 + t)*512 + kq*16);
        }
        const float* wp = Wy + (size_t)(kq*16)*512 + i*64 + 4*c4;
        float4 acc[16];
        #pragma unroll
        for (int r = 0; r < 16; ++r) acc[r] = make_float4(0.f,0.f,0.f,0.f);
        for (int kk = 0; kk < 16; ++kk){
            float4 wr = *(const float4*)(wp + (size_t)kk*512);
            #pragma unroll
            for (int r = 0; r < 16; ++r){
                float xr = ys_e[base[r] + kk];
                acc[r].x = fmaf(xr, wr.x, acc[r].x); acc[r].y = fmaf(xr, wr.y, acc[r].y);
                acc[r].z = fmaf(xr, wr.z, acc[r].z); acc[r].w = fmaf(xr, wr.w, acc[r].w);
            }
        }
        for (int r = 0; r < 16; ++r){
            float* cp = arena + tid*5;
            cp[0]=acc[r].x; cp[1]=acc[r].y; cp[2]=acc[r].z; cp[3]=acc[r].w;
            __syncthreads();
            if (tid < 64){
                int c = tid; float s = 0.f;
                #pragma unroll
                for (int q = 0; q < 32; ++q) s += arena[(q*16 + (c>>2))*5 + (c&3)];
                int rg = cc*16 + r, bb = rg >> 6, t = rg & 63;
                YWbP[(((size_t)w*2 + bb)*64 + t)*64 + c] = s + by[i*64 + c];
            }
            __syncthreads();
        }
    }

    // ---- pooled slice ----
    if (tid < 256){
        int bb = tid >> 7, c = i*128 + (tid & 127);
        float msum = 0.f;
        for (int l = 0; l < 64; ++l) msum += xml[bb][l];
        float a = 0.f;
        for (int l = 0; l < 64; ++l)
            a += xs_h[((size_t)(b0+bb)*64 + l)*1024 + c] * xml[bb][l];
        g_st(&pool_[bb*1024 + c], a / msum);
    }
    gbar();   // publish AXn + pooled + zeroed e

    // ---- s0 = tanh(pooled @ W_sinit + b) ----
    for (int k = tid; k < 2048; k += TPB) xv[k] = g_ld(&pool_[k]);
    __syncthreads();
    {
        int c4 = tid & 15, kq = tid >> 4;            // 32 kq x 32 k
        const float* wp = W_sinit + (size_t)(kq*32)*512 + i*64 + 4*c4;
        float4 A = make_float4(0.f,0.f,0.f,0.f), Bv = make_float4(0.f,0.f,0.f,0.f);
        for (int kk = 0; kk < 32; ++kk){
            float4 wr = *(const float4*)(wp + (size_t)kk*512);
            float xA = xv[kq*32 + kk], xB = xv[1024 + kq*32 + kk];
            A.x = fmaf(xA, wr.x, A.x); A.y = fmaf(xA, wr.y, A.y);
            A.z = fmaf(xA, wr.z, A.z); A.w = fmaf(xA, wr.w, A.w);
            Bv.x = fmaf(xB, wr.x, Bv.x); Bv.y = fmaf(xB, wr.y, Bv.y);
            Bv.z = fmaf(xB, wr.z, Bv.z); Bv.w = fmaf(xB, wr.w, Bv.w);
        }
        float* cp = comb + tid*9;
        cp[0]=A.x; cp[1]=A.y; cp[2]=A.z; cp[3]=A.w;
        cp[4]=Bv.x; cp[5]=Bv.y; cp[6]=Bv.z; cp[7]=Bv.w;
        __syncthreads();
        if (tid < 128){
            int bb = tid >> 6, c = tid & 63; float s = 0.f;
            #pragma unroll
            for (int q = 0; q < 32; ++q) s += comb[(q*16 + (c>>2))*9 + bb*4 + (c&3)];
            g_st(&s0_[bb*512 + i*64 + c], tanhf(s + b_sinit[i*64 + c]));
        }
        __syncthreads();
    }
    gbar();
    sal[0][tid] = g_ld(&s0_[tid]);
    sal[1][tid] = g_ld(&s0_[512 + tid]);
    __syncthreads();

    // ---- tmpH for t=0 ----
    {
        float r0 = gemv2(Wsm, 512, i*64, Wh_cell, 1536, i*192, 16,
                         &sal[0][0], &sal[1][0], 512);
        int bb = tid >> 8, c = tid & 255;
        if (c >= 64) g_st(&tmpH_[bb*1536 + i*192 + (c - 64)], r0);
    }
    gbar();

    // ======================= sequential scan (5 barriers/step) =======================
    for (int t = 0; t < 64; ++t){
        float ymr[2] = { ys_mask[(size_t)b0*64 + t], ys_mask[(size_t)(b0+1)*64 + t] };

        // ---- phase A+B: cell-GRU + qb slice (LOCAL) + partial-e + tmpHC slice ----
        {
            float th[2][3], ax[2][3], st[6];
            #pragma unroll
            for (int bb = 0; bb < 2; ++bb)
                #pragma unroll
                for (int g = 0; g < 3; ++g){
                    th[bb][g] = g_ld(&tmpH_[bb*1536 + g*512 + tid]);
                    ax[bb][g] = g_ld(&AXn[(((size_t)(b0+bb))*64 + t)*1536 + g*512 + tid]);
                    st[bb*3+g] = th[bb][g];
                }
            breduce(st, 6);
            float dv[2][3], st2[6];
            #pragma unroll
            for (int bb = 0; bb < 2; ++bb)
                #pragma unroll
                for (int g = 0; g < 3; ++g){
                    float mu = st[bb*3+g]*(1.f/512.f);
                    dv[bb][g] = th[bb][g] - mu;
                    st2[bb*3+g] = dv[bb][g]*dv[bb][g];
                }
            breduce(st2, 6);
            #pragma unroll
            for (int bb = 0; bb < 2; ++bb){
                float ah[3];
                #pragma unroll
                for (int g = 0; g < 3; ++g){
                    float var = st2[bb*3+g]*(1.f/512.f);
                    ah[g] = dv[bb][g]*rsqrtf(var + 1e-5f)*gh_cell[g*512 + tid];
                }
                float h  = sal[bb][tid];
                float r  = sigm(ax[bb][0] + ah[0]);
                float z  = sigm(ax[bb][1] + ah[1]);
                float hc = tanhf(ax[bb][2] + r*ah[2]);
                float hn = (1.f - z)*h + z*hc;
                sbl[bb][tid] = ymr[bb]*hn + (1.f - ymr[bb])*h;
            }
        }
        __syncthreads();
        {
            float ra = gemv2(Wq, 512, i*64, Wh_cond, 1536, i*192, 16,
                             &sbl[0][0], &sbl[1][0], 512);
            int bb = tid >> 8, c = tid & 255;
            if (c < 64) qbl[bb][c] = ra + bq[i*64 + c];
            else g_st(&tmpHC_[bb*1536 + i*192 + (c - 64)], ra);
        }
        __syncthreads();   // qbl visible
        {
            // partial e over my d-slice: 128 jobs (bb,l) x 4 threads x 16 d
            int jg = tid >> 2, dq = tid & 3;
            int bb = jg >> 6, l = jg & 63;
            float acc[8] = {0.f,0.f,0.f,0.f,0.f,0.f,0.f,0.f};
            #pragma unroll
            for (int u = 0; u < 16; ++u){
                int dd = dq*16 + u;
                float hid = tanhf(uhT[jg*64 + dd] + qbl[bb][dd]);
                float4 va = *(const float4*)&V_att[(size_t)(i*64 + dd)*8];
                float4 vb = *(const float4*)&V_att[(size_t)(i*64 + dd)*8 + 4];
                acc[0] = fmaf(hid, va.x, acc[0]); acc[1] = fmaf(hid, va.y, acc[1]);
                acc[2] = fmaf(hid, va.z, acc[2]); acc[3] = fmaf(hid, va.w, acc[3]);
                acc[4] = fmaf(hid, vb.x, acc[4]); acc[5] = fmaf(hid, vb.y, acc[5]);
                acc[6] = fmaf(hid, vb.z, acc[6]); acc[7] = fmaf(hid, vb.w, acc[7]);
            }
            #pragma unroll
            for (int h = 0; h < 8; ++h){
                acc[h] += __shfl_xor(acc[h], 1);
                acc[h] += __shfl_xor(acc[h], 2);
            }
            if (dq == 0){
                #pragma unroll
                for (int h = 0; h < 8; ++h)
                    __hip_atomic_fetch_add(&e_[(size_t)(bb*64 + l)*8 + h], acc[h],
                                           __ATOMIC_RELAXED, __HIP_MEMORY_SCOPE_AGENT);
            }
        }
        gbar();  // A (e complete, tmpHC published)

        // ---- phase C: softmax (head i; mask at read) + ctx0 slice ----
        if (wv < 2){
            int bb = wv;
            float mk = xml[bb][lane];
            float v = (mk > 0.f) ? g_ld(&e_[((size_t)bb*64 + lane)*8 + i]) : -1e9f;
            float mx = v;
            #pragma unroll
            for (int o = 32; o; o >>= 1) mx = fmaxf(mx, __shfl_xor(mx, o));
            float ex = expf(v - mx);
            float ss = ex;
            #pragma unroll
            for (int o = 32; o; o >>= 1) ss += __shfl_xor(ss, o);
            al[bb][lane] = ex / ss;
        }
        __syncthreads();
        {
            int kq = tid >> 6, job = tid & 63, bb = job >> 5, cg = job & 31;
            int c0 = i*128 + 4*cg;
            float4 a4 = make_float4(0.f,0.f,0.f,0.f);
            #pragma unroll
            for (int u = 0; u < 8; ++u){
                int l = kq*8 + u;
                float a = al[bb][l];
                float4 xw = *(const float4*)&xs_h[((size_t)(b0+bb)*64 + l)*1024 + c0];
                a4.x = fmaf(a, xw.x, a4.x); a4.y = fmaf(a, xw.y, a4.y);
                a4.z = fmaf(a, xw.z, a4.z); a4.w = fmaf(a, xw.w, a4.w);
            }
            float* cp = comb + tid*5;
            cp[0]=a4.x; cp[1]=a4.y; cp[2]=a4.z; cp[3]=a4.w;
            __syncthreads();
            if (tid < 256){
                int bb2 = tid >> 7, c = tid & 127; float s = 0.f;
                #pragma unroll
                for (int q = 0; q < 8; ++q) s += comb[(q*64 + bb2*32 + (c>>2))*5 + (c&3)];
                g_st(&ctx0_[bb2*1024 + i*128 + c], s);
            }
            __syncthreads();
        }
        gbar();  // C

        // ---- phase D: ctx = (ctx0 @ Wo + bo) * ym  + re-zero e for next step ----
        for (int k = tid; k < 2048; k += TPB) xv[k] = g_ld(&ctx0_[k]);
        for (int k = tid; k < 1024; k += TPB) g_st(&e_[k], 0.f);   // safe: e last read before gbar C
        __syncthreads();
        {
            int kq = tid >> 5, cg = tid & 31;        // 16 kq x 64 k, 32 cg x 4 cols
            int c0 = i*128 + 4*cg;
            const float* wp = Wo + (size_t)(kq*64)*1024 + c0;
            const float* xa = xv + kq*64;
            const float* xb = xv + 1024 + kq*64;
            float a0=0,a1=0,a2=0,a3=0, d0=0,d1=0,d2=0,d3=0;
            for (int kk = 0; kk < 64; kk += 16){
                float4 wr[16];
                #pragma unroll
                for (int u = 0; u < 16; ++u) wr[u] = *(const float4*)(wp + (size_t)(kk+u)*1024);
                #pragma unroll
                for (int u = 0; u < 16; ++u){
                    float xA = xa[kk+u], xB = xb[kk+u];
                    a0 = fmaf(xA, wr[u].x, a0); a1 = fmaf(xA, wr[u].y, a1);
                    a2 = fmaf(xA, wr[u].z, a2); a3 = fmaf(xA, wr[u].w, a3);
                    d0 = fmaf(xB, wr[u].x, d0); d1 = fmaf(xB, wr[u].y, d1);
                    d2 = fmaf(xB, wr[u].z, d2); d3 = fmaf(xB, wr[u].w, d3);
                }
            }
            float* cp = comb + tid*9;
            cp[0]=a0; cp[1]=a1; cp[2]=a2; cp[3]=a3;
            cp[4]=d0; cp[5]=d1; cp[6]=d2; cp[7]=d3;
            __syncthreads();
            if (tid < 256){
                int bb2 = tid >> 7, c = tid & 127; float s = 0.f;
                #pragma unroll
                for (int q = 0; q < 16; ++q) s += comb[(q*32 + (c>>2))*9 + bb2*4 + (c&3)];
                float ym2 = bb2 ? ymr[1] : ymr[0];
                g_st(&ctx_[bb2*1024 + i*128 + c], (s + bo[i*128 + c]) * ym2);
            }
            __syncthreads();
        }
        gbar();  // D

        // ---- phase E: tmpXC (Wx_cond) + outc (Wc) from ctx ----
        for (int k = tid; k < 2048; k += TPB) xv[k] = g_ld(&ctx_[k]);
        __syncthreads();
        {
            float re = gemv2(Wx_cond, 1536, i*192, Wc, 512, i*64, 48,
                             &xv[0], &xv[1024], 1024);
            int bb = tid >> 8, c = tid & 255;
            if (c < 192){
                g_st(&tmpXC_[bb*1536 + i*192 + c], re);
            } else {
                outcl[bb][c - 192] = re;
            }
        }
        gbar();  // E

        // ---- phase F: cond-GRU (redundant, two-pass LN) + out + tmpH(t+1) ----
        {
            float tx[2][3], th[2][3], st[12];
            #pragma unroll
            for (int bb = 0; bb < 2; ++bb)
                #pragma unroll
                for (int g = 0; g < 3; ++g){
                    tx[bb][g] = g_ld(&tmpXC_[bb*1536 + g*512 + tid]);
                    th[bb][g] = g_ld(&tmpHC_[bb*1536 + g*512 + tid]);
                    st[bb*3+g]     = tx[bb][g];
                    st[6 + bb*3+g] = th[bb][g];
                }
            breduce(st, 12);
            float dx[2][3], dh[2][3], st2[12];
            #pragma unroll
            for (int bb = 0; bb < 2; ++bb)
                #pragma unroll
                for (int g = 0; g < 3; ++g){
                    float mux = st[bb*3+g]*(1.f/512.f);
                    float muh = st[6 + bb*3+g]*(1.f/512.f);
                    dx[bb][g] = tx[bb][g] - mux;
                    dh[bb][g] = th[bb][g] - muh;
                    st2[bb*3+g]     = dx[bb][g]*dx[bb][g];
                    st2[6 + bb*3+g] = dh[bb][g]*dh[bb][g];
                }
            breduce(st2, 12);
            float snew[2];
            #pragma unroll
            for (int bb = 0; bb < 2; ++bb){
                float axc[3], ahc[3];
                #pragma unroll
                for (int g = 0; g < 3; ++g){
                    int c2 = g*512 + tid;
                    float vax = st2[bb*3+g]*(1.f/512.f);
                    float vah = st2[6 + bb*3+g]*(1.f/512.f);
                    axc[g] = dx[bb][g]*rsqrtf(vax + 1e-5f)*gx_cond[c2] + bx_cond[c2];
                    ahc[g] = dh[bb][g]*rsqrtf(vah + 1e-5f)*gh_cond[c2];
                }
                float h  = sbl[bb][tid];
                float r  = sigm(axc[0] + ahc[0]);
                float z  = sigm(axc[1] + ahc[1]);
                float hc = tanhf(axc[2] + r*ahc[2]);
                float hn = (1.f - z)*h + z*hc;
                snew[bb] = ymr[bb]*hn + (1.f - ymr[bb])*h;
            }
            sal[0][tid] = snew[0];
            sal[1][tid] = snew[1];
        }
        __syncthreads();
        {
            float rf = gemv2(Wsm, 512, i*64, Wh_cell, 1536, i*192, 16,
                             &sal[0][0], &sal[1][0], 512);
            int bb = tid >> 8, c = tid & 255;
            if (c < 64){
                int col = i*64 + c;
                float ymf = bb ? ymr[1] : ymr[0];
                float v = rf + YWbP[(((size_t)w*2 + bb)*64 + t)*64 + c]
                        + outcl[bb][c] + bc[col] + bs[col];
                out[(((size_t)(b0+bb))*64 + t)*512 + col] = tanhf(v)*ymf;
            } else {
                g_st(&tmpH_[bb*1536 + i*192 + (c - 64)], rf);
            }
        }
        gbar();  // F
    }
}

// ---------------------------------------------------------------------------
extern "C" void kernel_launch(void* const* d_in, const int* in_sizes, int n_in,
                              void* d_out, int out_size, void* d_ws, size_t ws_size,
                              hipStream_t stream)
{
    // re-zero barrier counters on every graph replay
    hipMemsetAsync(d_ws, 0, 4096, stream);

    decoder_persistent<<<dim3(NWG), dim3(TPB), 0, stream>>>(
        (const float*)d_in[0],  (const float*)d_in[1],  (const float*)d_in[2],
        (const float*)d_in[3],  (const float*)d_in[4],  (const float*)d_in[5],
        (const float*)d_in[6],  (const float*)d_in[7],  (const float*)d_in[8],
        (const float*)d_in[9],  (const float*)d_in[10], (const float*)d_in[11],
        (const float*)d_in[12], (const float*)d_in[13], (const float*)d_in[14],
        (const float*)d_in[15], (const float*)d_in[16], (const float*)d_in[17],
        (const float*)d_in[18], (const float*)d_in[19], (const float*)d_in[20],
        (const float*)d_in[21], (const float*)d_in[22], (const float*)d_in[23],
        (const float*)d_in[24], (const float*)d_in[25], (const float*)d_in[26],
        (const float*)d_in[27],
        (float*)d_out, (float*)d_ws);
}

// Round 10
// 6582.137 us; speedup vs baseline: 1.7390x; 1.5112x over previous
//
#include <hip/hip_runtime.h>
#include <math.h>

#define TPB 512
#define NWG 256   // 32 groups x 8 WGs, 1 WG/CU

// Cross-WG traffic: agent-scope atomics (coherence point, no stale-L2 reads).
// Barrier arrive = RELEASE, spin = ACQUIRE (proven R8/R9) at 8 arrivals (cheap).
__device__ __forceinline__ float g_ld(const float* p){
    return __hip_atomic_load(p, __ATOMIC_RELAXED, __HIP_MEMORY_SCOPE_AGENT);
}
__device__ __forceinline__ void g_st(float* p, float v){
    __hip_atomic_store(p, v, __ATOMIC_RELAXED, __HIP_MEMORY_SCOPE_AGENT);
}
__device__ __forceinline__ float sigm(float x){ return 1.f/(1.f+expf(-x)); }

__global__ __launch_bounds__(TPB, 4) void decoder_persistent(
    const float* __restrict__ xs_h, const float* __restrict__ ys_e,
    const float* __restrict__ xs_mask, const float* __restrict__ ys_mask,
    const float* __restrict__ W_sinit, const float* __restrict__ b_sinit,
    const float* __restrict__ W_keys,
    const float* __restrict__ Wx_cell, const float* __restrict__ bx_cell,
    const float* __restrict__ gx_cell, const float* __restrict__ Wh_cell,
    const float* __restrict__ gh_cell,
    const float* __restrict__ Wx_cond, const float* __restrict__ bx_cond,
    const float* __restrict__ gx_cond, const float* __restrict__ Wh_cond,
    const float* __restrict__ gh_cond,
    const float* __restrict__ Wq, const float* __restrict__ bq,
    const float* __restrict__ V_att, const float* __restrict__ Wo,
    const float* __restrict__ bo, const float* __restrict__ Wy,
    const float* __restrict__ by, const float* __restrict__ Wc,
    const float* __restrict__ bc, const float* __restrict__ Wsm,
    const float* __restrict__ bs,
    float* __restrict__ out, float* __restrict__ ws)
{
    const int w    = blockIdx.x;
    const int tid  = threadIdx.x;
    const int lane = tid & 63, wv = tid >> 6;
    const int i    = w & 7;          // column slice (== XCD under %8 mapping; perf-only)
    const int grp  = w >> 3;         // group 0..31
    const int b0   = grp * 2;        // this group's 2 batch rows

    // ---------------- workspace layout (floats), total ~11.08M = 44.3 MB ----------------
    unsigned* cntg = (unsigned*)ws + (size_t)grp * 16;   // group barrier ctr (64B padded)
    float* AXn  = ws + 1024;                             // [64][64][1536] LN'd x-branch
    float* uhP  = AXn  + (size_t)64*64*1536;             // [256][16][512] WG-private
    float* YWbP = uhP  + (size_t)256*16*512;             // [256][2][64][64] WG-private
    float* PB   = YWbP + (size_t)256*2*64*64;            // [32][18432] per-group block
    float* pb     = PB + (size_t)grp * 18432;
    float* tmpH_  = pb;            // [2][1536]
    float* tmpHC_ = pb + 3072;     // [2][1536]
    float* tmpXC_ = pb + 6144;     // [2][1536]
    float* qb_    = pb + 9216;     // [2][512]
    float* e_     = pb + 10240;    // [2][64][8]
    float* ctx0_  = pb + 11264;    // [2][1024]
    float* ctx_   = pb + 13312;    // [2][1024]
    float* pool_  = pb + 15360;    // [2][1024]
    float* s0_    = pb + 17408;    // [2][512]

    // ---------------- LDS (~125 KB; 1 WG/CU) ----------------
    __shared__ float sal[2][512];    // carry s_t (identical in all 8 WGs)
    __shared__ float sbl[2][512];    // cell-GRU "state"
    __shared__ float al[2][64];      // alpha for head i
    __shared__ float outcl[2][64];   // ctx@Wc slice
    __shared__ float xml[2][64];     // xs_mask rows
    __shared__ float red[8][24];
    __shared__ float red2[24];
    __shared__ float xsl[2*64*128];  // xs_h slice cache: [bb][l][cc], cols i*128..+128 (64 KB)
    __shared__ float arena[13056];   // staging + combine scratch
    float* xv   = arena;             // [2][1024] staging
    float* comb = arena + 2048;      // combine region (<= 4608 floats)

    unsigned gen = 0;
    auto gbar = [&](){
        __syncthreads();             // vmcnt(0) drain of this WG's stores
        ++gen;
        if (tid == 0){
            __hip_atomic_fetch_add(cntg, 1u, __ATOMIC_RELEASE, __HIP_MEMORY_SCOPE_AGENT);
            while (__hip_atomic_load(cntg, __ATOMIC_ACQUIRE, __HIP_MEMORY_SCOPE_AGENT) < 8u*gen)
                __builtin_amdgcn_s_sleep(2);
        }
        asm volatile("" ::: "memory");
        __syncthreads();
    };

    auto breduce = [&](float* v, int nv){
        for (int n = 0; n < nv; ++n){
            float x = v[n];
            #pragma unroll
            for (int o = 32; o; o >>= 1) x += __shfl_xor(x, o);
            v[n] = x;
        }
        if (lane == 0) for (int n = 0; n < nv; ++n) red[wv][n] = v[n];
        __syncthreads();
        if (tid < nv){ float s = 0.f; for (int q = 0; q < 8; ++q) s += red[q][tid]; red2[tid] = s; }
        __syncthreads();
        for (int n = 0; n < nv; ++n) v[n] = red2[n];
    };

    // dual-matrix sliced GEMV for 2 batch rows, 256 output cols, K-split 8.
    auto gemv2 = [&](const float* Wa, int lda, int ca,
                     const float* Wb, int ldb, int cb, int CGA,
                     const float* x0, const float* x1, int K)->float{
        int cg = tid & 63, kq = tid >> 6;
        const float* W; int ld, col;
        if (cg < CGA){ W = Wa; ld = lda; col = ca + 4*cg; }
        else         { W = Wb; ld = ldb; col = cb + 4*(cg - CGA); }
        int Kq = K >> 3;
        const float* wp = W + (size_t)(kq*Kq)*ld + col;
        const float* xa = x0 + kq*Kq;
        const float* xb = x1 + kq*Kq;
        float a0=0,a1=0,a2=0,a3=0, c0=0,c1=0,c2=0,c3=0;
        for (int kk = 0; kk < Kq; kk += 8){
            float4 wr[8];
            #pragma unroll
            for (int u = 0; u < 8; ++u) wr[u] = *(const float4*)(wp + (size_t)(kk+u)*ld);
            #pragma unroll
            for (int u = 0; u < 8; ++u){
                float xA = xa[kk+u], xB = xb[kk+u];
                a0 = fmaf(xA, wr[u].x, a0); a1 = fmaf(xA, wr[u].y, a1);
                a2 = fmaf(xA, wr[u].z, a2); a3 = fmaf(xA, wr[u].w, a3);
                c0 = fmaf(xB, wr[u].x, c0); c1 = fmaf(xB, wr[u].y, c1);
                c2 = fmaf(xB, wr[u].z, c2); c3 = fmaf(xB, wr[u].w, c3);
            }
        }
        float* cp = comb + tid*9;
        cp[0]=a0; cp[1]=a1; cp[2]=a2; cp[3]=a3;
        cp[4]=c0; cp[5]=c1; cp[6]=c2; cp[7]=c3;
        __syncthreads();
        int bb = tid >> 8, c = tid & 255, cgq = c >> 2, j = c & 3;
        float s = 0.f;
        #pragma unroll
        for (int q = 0; q < 8; ++q) s += comb[(q*64 + cgq)*9 + bb*4 + j];
        __syncthreads();
        return s;
    };

    // ======================= precompute =======================
    if (tid < 128) xml[tid>>6][tid&63] = xs_mask[(size_t)(b0 + (tid>>6))*64 + (tid&63)];
    // xs_h slice cache: cols [i*128, i*128+128) for both batch rows, all 64 l.
    for (int k = tid; k < 16384; k += TPB){
        int bb = k >> 13, rem = k & 8191, l = rem >> 7, cc = rem & 127;
        xsl[k] = xs_h[((size_t)((b0+bb)*64 + l))*1024 + i*128 + cc];
    }
    __syncthreads();

    // ---- uh (private): 16 jobs (2b x 8 l), 512 cols, K=1024; W_keys read once ----
    {
        int c4 = tid & 127, kq = tid >> 7;           // 4 kq x 256 k
        unsigned base[16];
        #pragma unroll
        for (int j = 0; j < 16; ++j){
            int bb = j >> 3, l = i*8 + (j & 7);
            base[j] = (unsigned)(((b0+bb)*64 + l)*1024 + kq*256);
        }
        const float* wp = W_keys + (size_t)(kq*256)*512 + 4*c4;
        float4 acc[16];
        #pragma unroll
        for (int j = 0; j < 16; ++j) acc[j] = make_float4(0.f,0.f,0.f,0.f);
        for (int kk = 0; kk < 256; ++kk){
            float4 wr = *(const float4*)(wp + (size_t)kk*512);
            #pragma unroll
            for (int j = 0; j < 16; ++j){
                float xr = xs_h[base[j] + kk];
                acc[j].x = fmaf(xr, wr.x, acc[j].x); acc[j].y = fmaf(xr, wr.y, acc[j].y);
                acc[j].z = fmaf(xr, wr.z, acc[j].z); acc[j].w = fmaf(xr, wr.w, acc[j].w);
            }
        }
        for (int r = 0; r < 16; ++r){
            float* cp = arena + tid*5;
            cp[0]=acc[r].x; cp[1]=acc[r].y; cp[2]=acc[r].z; cp[3]=acc[r].w;
            __syncthreads();
            int c = tid; float s = 0.f;
            #pragma unroll
            for (int q = 0; q < 4; ++q) s += arena[(q*128 + (c>>2))*5 + (c&3)];
            uhP[((size_t)w*16 + r)*512 + c] = s;
            __syncthreads();
        }
    }

    // ---- AXn (published to group): 16 rows (2b x 8 t), LN(ys_e@Wx_cell)*gx+bx ----
    // TWO-PASS LN variance (round-3 lesson).
    for (int g = 0; g < 3; ++g){
        int c4 = tid & 127, kq = tid >> 7;           // 4 kq x 128 k
        unsigned base[16];
        #pragma unroll
        for (int j = 0; j < 16; ++j){
            int bb = j >> 3, t = i*8 + (j & 7);
            base[j] = (unsigned)(((b0+bb)*64 + t)*512 + kq*128);
        }
        const float* wp = Wx_cell + (size_t)(kq*128)*1536 + g*512 + 4*c4;
        float4 acc[16];
        #pragma unroll
        for (int j = 0; j < 16; ++j) acc[j] = make_float4(0.f,0.f,0.f,0.f);
        for (int kk = 0; kk < 128; ++kk){
            float4 wr = *(const float4*)(wp + (size_t)kk*1536);
            #pragma unroll
            for (int j = 0; j < 16; ++j){
                float xr = ys_e[base[j] + kk];
                acc[j].x = fmaf(xr, wr.x, acc[j].x); acc[j].y = fmaf(xr, wr.y, acc[j].y);
                acc[j].z = fmaf(xr, wr.z, acc[j].z); acc[j].w = fmaf(xr, wr.w, acc[j].w);
            }
        }
        for (int r = 0; r < 16; ++r){
            float* cp = arena + tid*5;
            cp[0]=acc[r].x; cp[1]=acc[r].y; cp[2]=acc[r].z; cp[3]=acc[r].w;
            __syncthreads();
            int c = tid; float val = 0.f;
            #pragma unroll
            for (int q = 0; q < 4; ++q) val += arena[(q*128 + (c>>2))*5 + (c&3)];
            float s1[1] = { val };
            breduce(s1, 1);
            float mu = s1[0]*(1.f/512.f);
            float d = val - mu;
            float s2[1] = { d*d };
            breduce(s2, 1);
            float rstd = rsqrtf(s2[0]*(1.f/512.f) + 1e-5f);
            int bb = r >> 3, t = i*8 + (r & 7), cg2 = g*512 + c;
            g_st(&AXn[(((size_t)(b0+bb))*64 + t)*1536 + cg2],
                 d*rstd*gx_cell[cg2] + bx_cell[cg2]);
            __syncthreads();
        }
    }

    // ---- YWb (private): 128 rows (2b x 64 t) in 8 chunks, 64-col slice ----
    for (int cc = 0; cc < 8; ++cc){
        int c4 = tid & 15, kq = tid >> 4;            // 32 kq x 16 k
        unsigned base[16];
        #pragma unroll
        for (int r = 0; r < 16; ++r){
            int rg = cc*16 + r, bb = rg >> 6, t = rg & 63;
            base[r] = (unsigned)(((b0+bb)*64 + t)*512 + kq*16);
        }
        const float* wp = Wy + (size_t)(kq*16)*512 + i*64 + 4*c4;
        float4 acc[16];
        #pragma unroll
        for (int r = 0; r < 16; ++r) acc[r] = make_float4(0.f,0.f,0.f,0.f);
        for (int kk = 0; kk < 16; ++kk){
            float4 wr = *(const float4*)(wp + (size_t)kk*512);
            #pragma unroll
            for (int r = 0; r < 16; ++r){
                float xr = ys_e[base[r] + kk];
                acc[r].x = fmaf(xr, wr.x, acc[r].x); acc[r].y = fmaf(xr, wr.y, acc[r].y);
                acc[r].z = fmaf(xr, wr.z, acc[r].z); acc[r].w = fmaf(xr, wr.w, acc[r].w);
            }
        }
        for (int r = 0; r < 16; ++r){
            float* cp = arena + tid*5;
            cp[0]=acc[r].x; cp[1]=acc[r].y; cp[2]=acc[r].z; cp[3]=acc[r].w;
            __syncthreads();
            if (tid < 64){
                int c = tid; float s = 0.f;
                #pragma unroll
                for (int q = 0; q < 32; ++q) s += arena[(q*16 + (c>>2))*5 + (c&3)];
                int rg = cc*16 + r, bb = rg >> 6, t = rg & 63;
                YWbP[(((size_t)w*2 + bb)*64 + t)*64 + c] = s + by[i*64 + c];
            }
            __syncthreads();
        }
    }

    // ---- pooled slice (from LDS cache; bit-identical values/order) ----
    if (tid < 256){
        int bb = tid >> 7, c = tid & 127;
        float msum = 0.f;
        for (int l = 0; l < 64; ++l) msum += xml[bb][l];
        float a = 0.f;
        for (int l = 0; l < 64; ++l)
            a += xsl[(bb*64 + l)*128 + c] * xml[bb][l];
        g_st(&pool_[bb*1024 + i*128 + c], a / msum);
    }
    gbar();   // publish AXn + pooled

    // ---- s0 = tanh(pooled @ W_sinit + b) ----
    for (int k = tid; k < 2048; k += TPB) xv[k] = g_ld(&pool_[k]);
    __syncthreads();
    {
        int c4 = tid & 15, kq = tid >> 4;            // 32 kq x 32 k
        const float* wp = W_sinit + (size_t)(kq*32)*512 + i*64 + 4*c4;
        float4 A = make_float4(0.f,0.f,0.f,0.f), Bv = make_float4(0.f,0.f,0.f,0.f);
        for (int kk = 0; kk < 32; ++kk){
            float4 wr = *(const float4*)(wp + (size_t)kk*512);
            float xA = xv[kq*32 + kk], xB = xv[1024 + kq*32 + kk];
            A.x = fmaf(xA, wr.x, A.x); A.y = fmaf(xA, wr.y, A.y);
            A.z = fmaf(xA, wr.z, A.z); A.w = fmaf(xA, wr.w, A.w);
            Bv.x = fmaf(xB, wr.x, Bv.x); Bv.y = fmaf(xB, wr.y, Bv.y);
            Bv.z = fmaf(xB, wr.z, Bv.z); Bv.w = fmaf(xB, wr.w, Bv.w);
        }
        float* cp = comb + tid*9;
        cp[0]=A.x; cp[1]=A.y; cp[2]=A.z; cp[3]=A.w;
        cp[4]=Bv.x; cp[5]=Bv.y; cp[6]=Bv.z; cp[7]=Bv.w;
        __syncthreads();
        if (tid < 128){
            int bb = tid >> 6, c = tid & 63; float s = 0.f;
            #pragma unroll
            for (int q = 0; q < 32; ++q) s += comb[(q*16 + (c>>2))*9 + bb*4 + (c&3)];
            g_st(&s0_[bb*512 + i*64 + c], tanhf(s + b_sinit[i*64 + c]));
        }
        __syncthreads();
    }
    gbar();
    sal[0][tid] = g_ld(&s0_[tid]);
    sal[1][tid] = g_ld(&s0_[512 + tid]);
    __syncthreads();

    // ---- tmpH for t=0 ----
    {
        float r0 = gemv2(Wsm, 512, i*64, Wh_cell, 1536, i*192, 16,
                         &sal[0][0], &sal[1][0], 512);
        int bb = tid >> 8, c = tid & 255;
        if (c >= 64) g_st(&tmpH_[bb*1536 + i*192 + (c - 64)], r0);
    }
    gbar();

    // ======================= sequential scan =======================
    for (int t = 0; t < 64; ++t){
        float ymr[2] = { ys_mask[(size_t)b0*64 + t], ys_mask[(size_t)(b0+1)*64 + t] };

        // ---- phase A: cell-GRU (redundant, two-pass LN) + qb/tmpHC slice ----
        {
            float th[2][3], ax[2][3], st[6];
            #pragma unroll
            for (int bb = 0; bb < 2; ++bb)
                #pragma unroll
                for (int g = 0; g < 3; ++g){
                    th[bb][g] = g_ld(&tmpH_[bb*1536 + g*512 + tid]);
                    ax[bb][g] = g_ld(&AXn[(((size_t)(b0+bb))*64 + t)*1536 + g*512 + tid]);
                    st[bb*3+g] = th[bb][g];
                }
            breduce(st, 6);
            float dv[2][3], st2[6];
            #pragma unroll
            for (int bb = 0; bb < 2; ++bb)
                #pragma unroll
                for (int g = 0; g < 3; ++g){
                    float mu = st[bb*3+g]*(1.f/512.f);
                    dv[bb][g] = th[bb][g] - mu;
                    st2[bb*3+g] = dv[bb][g]*dv[bb][g];
                }
            breduce(st2, 6);
            #pragma unroll
            for (int bb = 0; bb < 2; ++bb){
                float ah[3];
                #pragma unroll
                for (int g = 0; g < 3; ++g){
                    float var = st2[bb*3+g]*(1.f/512.f);
                    ah[g] = dv[bb][g]*rsqrtf(var + 1e-5f)*gh_cell[g*512 + tid];
                }
                float h  = sal[bb][tid];
                float r  = sigm(ax[bb][0] + ah[0]);
                float z  = sigm(ax[bb][1] + ah[1]);
                float hc = tanhf(ax[bb][2] + r*ah[2]);
                float hn = (1.f - z)*h + z*hc;
                sbl[bb][tid] = ymr[bb]*hn + (1.f - ymr[bb])*h;
            }
        }
        __syncthreads();
        {
            float ra = gemv2(Wq, 512, i*64, Wh_cond, 1536, i*192, 16,
                             &sbl[0][0], &sbl[1][0], 512);
            int bb = tid >> 8, c = tid & 255;
            if (c < 64){ int col = i*64 + c; g_st(&qb_[bb*512 + col], ra + bq[col]); }
            else g_st(&tmpHC_[bb*1536 + i*192 + (c - 64)], ra);
        }
        gbar();  // A

        // ---- phase B: attention scores for my 16 (b,l) jobs ----
        for (int k = tid; k < 1024; k += TPB) xv[k] = g_ld(&qb_[k]);
        __syncthreads();
        for (int jj = wv; jj < 16; jj += 8){
            int bb = jj >> 3, l = i*8 + (jj & 7);
            float acc[8] = {0.f,0.f,0.f,0.f,0.f,0.f,0.f,0.f};
            #pragma unroll
            for (int u = 0; u < 8; ++u){
                int d = u*64 + lane;
                float hid = tanhf(uhP[((size_t)w*16 + jj)*512 + d] + xv[bb*512 + d]);
                float4 va = *(const float4*)&V_att[(size_t)d*8];
                float4 vb = *(const float4*)&V_att[(size_t)d*8 + 4];
                acc[0] = fmaf(hid, va.x, acc[0]); acc[1] = fmaf(hid, va.y, acc[1]);
                acc[2] = fmaf(hid, va.z, acc[2]); acc[3] = fmaf(hid, va.w, acc[3]);
                acc[4] = fmaf(hid, vb.x, acc[4]); acc[5] = fmaf(hid, vb.y, acc[5]);
                acc[6] = fmaf(hid, vb.z, acc[6]); acc[7] = fmaf(hid, vb.w, acc[7]);
            }
            #pragma unroll
            for (int h = 0; h < 8; ++h)
                #pragma unroll
                for (int o = 32; o; o >>= 1) acc[h] += __shfl_xor(acc[h], o);
            if (lane == 0){
                float mk = xml[bb][l];
                #pragma unroll
                for (int h = 0; h < 8; ++h)
                    g_st(&e_[((size_t)bb*64 + l)*8 + h], (mk > 0.f) ? acc[h] : -1e9f);
            }
        }
        gbar();  // B

        // ---- phase C: softmax (head i) + ctx0 slice (xs_h from LDS cache) ----
        if (wv < 2){
            int bb = wv;
            float v = g_ld(&e_[((size_t)bb*64 + lane)*8 + i]);
            float mx = v;
            #pragma unroll
            for (int o = 32; o; o >>= 1) mx = fmaxf(mx, __shfl_xor(mx, o));
            float ex = expf(v - mx);
            float ss = ex;
            #pragma unroll
            for (int o = 32; o; o >>= 1) ss += __shfl_xor(ss, o);
            al[bb][lane] = ex / ss;
        }
        __syncthreads();
        {
            int kq = tid >> 6, job = tid & 63, bb = job >> 5, cg = job & 31;
            float4 a4 = make_float4(0.f,0.f,0.f,0.f);
            #pragma unroll
            for (int u = 0; u < 8; ++u){
                int l = kq*8 + u;
                float a = al[bb][l];
                float4 xw = *(const float4*)&xsl[((bb*64 + l) << 7) + 4*cg];
                a4.x = fmaf(a, xw.x, a4.x); a4.y = fmaf(a, xw.y, a4.y);
                a4.z = fmaf(a, xw.z, a4.z); a4.w = fmaf(a, xw.w, a4.w);
            }
            float* cp = comb + tid*5;
            cp[0]=a4.x; cp[1]=a4.y; cp[2]=a4.z; cp[3]=a4.w;
            __syncthreads();
            if (tid < 256){
                int bb2 = tid >> 7, c = tid & 127; float s = 0.f;
                #pragma unroll
                for (int q = 0; q < 8; ++q) s += comb[(q*64 + bb2*32 + (c>>2))*5 + (c&3)];
                g_st(&ctx0_[bb2*1024 + i*128 + c], s);
            }
            __syncthreads();
        }
        gbar();  // C

        // ---- phase D: ctx = (ctx0 @ Wo + bo) * ym  (direct Wo, K-split 16) ----
        for (int k = tid; k < 2048; k += TPB) xv[k] = g_ld(&ctx0_[k]);
        __syncthreads();
        {
            int kq = tid >> 5, cg = tid & 31;        // 16 kq x 64 k, 32 cg x 4 cols
            int c0 = i*128 + 4*cg;
            const float* wp = Wo + (size_t)(kq*64)*1024 + c0;
            const float* xa = xv + kq*64;
            const float* xb = xv + 1024 + kq*64;
            float a0=0,a1=0,a2=0,a3=0, d0=0,d1=0,d2=0,d3=0;
            for (int kk = 0; kk < 64; kk += 8){
                float4 wr[8];
                #pragma unroll
                for (int u = 0; u < 8; ++u) wr[u] = *(const float4*)(wp + (size_t)(kk+u)*1024);
                #pragma unroll
                for (int u = 0; u < 8; ++u){
                    float xA = xa[kk+u], xB = xb[kk+u];
                    a0 = fmaf(xA, wr[u].x, a0); a1 = fmaf(xA, wr[u].y, a1);
                    a2 = fmaf(xA, wr[u].z, a2); a3 = fmaf(xA, wr[u].w, a3);
                    d0 = fmaf(xB, wr[u].x, d0); d1 = fmaf(xB, wr[u].y, d1);
                    d2 = fmaf(xB, wr[u].z, d2); d3 = fmaf(xB, wr[u].w, d3);
                }
            }
            float* cp = comb + tid*9;
            cp[0]=a0; cp[1]=a1; cp[2]=a2; cp[3]=a3;
            cp[4]=d0; cp[5]=d1; cp[6]=d2; cp[7]=d3;
            __syncthreads();
            if (tid < 256){
                int bb2 = tid >> 7, c = tid & 127; float s = 0.f;
                #pragma unroll
                for (int q = 0; q < 16; ++q) s += comb[(q*32 + (c>>2))*9 + bb2*4 + (c&3)];
                float ym2 = bb2 ? ymr[1] : ymr[0];
                g_st(&ctx_[bb2*1024 + i*128 + c], (s + bo[i*128 + c]) * ym2);
            }
            __syncthreads();
        }
        gbar();  // D

        // ---- phase E: tmpXC (Wx_cond) + outc (Wc) from ctx ----
        for (int k = tid; k < 2048; k += TPB) xv[k] = g_ld(&ctx_[k]);
        __syncthreads();
        {
            float re = gemv2(Wx_cond, 1536, i*192, Wc, 512, i*64, 48,
                             &xv[0], &xv[1024], 1024);
            int bb = tid >> 8, c = tid & 255;
            if (c < 192){
                g_st(&tmpXC_[bb*1536 + i*192 + c], re);
            } else {
                outcl[bb][c - 192] = re;
            }
        }
        gbar();  // E

        // ---- phase F: cond-GRU (redundant, two-pass LN) + out + tmpH(t+1) ----
        {
            float tx[2][3], th[2][3], st[12];
            #pragma unroll
            for (int bb = 0; bb < 2; ++bb)
                #pragma unroll
                for (int g = 0; g < 3; ++g){
                    tx[bb][g] = g_ld(&tmpXC_[bb*1536 + g*512 + tid]);
                    th[bb][g] = g_ld(&tmpHC_[bb*1536 + g*512 + tid]);
                    st[bb*3+g]     = tx[bb][g];
                    st[6 + bb*3+g] = th[bb][g];
                }
            breduce(st, 12);
            float dx[2][3], dh[2][3], st2[12];
            #pragma unroll
            for (int bb = 0; bb < 2; ++bb)
                #pragma unroll
                for (int g = 0; g < 3; ++g){
                    float mux = st[bb*3+g]*(1.f/512.f);
                    float muh = st[6 + bb*3+g]*(1.f/512.f);
                    dx[bb][g] = tx[bb][g] - mux;
                    dh[bb][g] = th[bb][g] - muh;
                    st2[bb*3+g]     = dx[bb][g]*dx[bb][g];
                    st2[6 + bb*3+g] = dh[bb][g]*dh[bb][g];
                }
            breduce(st2, 12);
            float snew[2];
            #pragma unroll
            for (int bb = 0; bb < 2; ++bb){
                float axc[3], ahc[3];
                #pragma unroll
                for (int g = 0; g < 3; ++g){
                    int c2 = g*512 + tid;
                    float vax = st2[bb*3+g]*(1.f/512.f);
                    float vah = st2[6 + bb*3+g]*(1.f/512.f);
                    axc[g] = dx[bb][g]*rsqrtf(vax + 1e-5f)*gx_cond[c2] + bx_cond[c2];
                    ahc[g] = dh[bb][g]*rsqrtf(vah + 1e-5f)*gh_cond[c2];
                }
                float h  = sbl[bb][tid];
                float r  = sigm(axc[0] + ahc[0]);
                float z  = sigm(axc[1] + ahc[1]);
                float hc = tanhf(axc[2] + r*ahc[2]);
                float hn = (1.f - z)*h + z*hc;
                snew[bb] = ymr[bb]*hn + (1.f - ymr[bb])*h;
            }
            sal[0][tid] = snew[0];
            sal[1][tid] = snew[1];
        }
        __syncthreads();
        {
            float rf = gemv2(Wsm, 512, i*64, Wh_cell, 1536, i*192, 16,
                             &sal[0][0], &sal[1][0], 512);
            int bb = tid >> 8, c = tid & 255;
            if (c < 64){
                int col = i*64 + c;
                float ymf = bb ? ymr[1] : ymr[0];
                float v = rf + YWbP[(((size_t)w*2 + bb)*64 + t)*64 + c]
                        + outcl[bb][c] + bc[col] + bs[col];
                out[(((size_t)(b0+bb))*64 + t)*512 + col] = tanhf(v)*ymf;
            } else {
                g_st(&tmpH_[bb*1536 + i*192 + (c - 64)], rf);
            }
        }
        gbar();  // F
    }
}

// ---------------------------------------------------------------------------
extern "C" void kernel_launch(void* const* d_in, const int* in_sizes, int n_in,
                              void* d_out, int out_size, void* d_ws, size_t ws_size,
                              hipStream_t stream)
{
    // re-zero barrier counters on every graph replay
    hipMemsetAsync(d_ws, 0, 4096, stream);

    decoder_persistent<<<dim3(NWG), dim3(TPB), 0, stream>>>(
        (const float*)d_in[0],  (const float*)d_in[1],  (const float*)d_in[2],
        (const float*)d_in[3],  (const float*)d_in[4],  (const float*)d_in[5],
        (const float*)d_in[6],  (const float*)d_in[7],  (const float*)d_in[8],
        (const float*)d_in[9],  (const float*)d_in[10], (const float*)d_in[11],
        (const float*)d_in[12], (const float*)d_in[13], (const float*)d_in[14],
        (const float*)d_in[15], (const float*)d_in[16], (const float*)d_in[17],
        (const float*)d_in[18], (const float*)d_in[19], (const float*)d_in[20],
        (const float*)d_in[21], (const float*)d_in[22], (const float*)d_in[23],
        (const float*)d_in[24], (const float*)d_in[25], (const float*)d_in[26],
        (const float*)d_in[27],
        (float*)d_out, (float*)d_ws);
}

// Round 12
// 5995.798 us; speedup vs baseline: 1.9090x; 1.0978x over previous
//
#include <hip/hip_runtime.h>
#include <math.h>

#define TPB 512
#define NWG 256   // 32 groups x 8 WGs, 1 WG/CU

// Cross-WG protocol (empirically settled over R4-R11):
//   - data moves via agent-scope RELAXED atomic ld/st (g_ld/g_st)
//   - barrier arrive = RELEASE fetch_add (writes back this WG's published stores)
//   - spin = RELAXED polls (cheap), then ONE ACQUIRE fence after the final
//     observation (synchronizes-with all 8 releases; invalidates stale lines)
// R10 (acquire-per-poll) passed but paid ~4us/barrier; R11 (fully relaxed)
// RACED (absmax 0.021). This is the minimal sound form.
__device__ __forceinline__ float g_ld(const float* p){
    return __hip_atomic_load(p, __ATOMIC_RELAXED, __HIP_MEMORY_SCOPE_AGENT);
}
__device__ __forceinline__ void g_st(float* p, float v){
    __hip_atomic_store(p, v, __ATOMIC_RELAXED, __HIP_MEMORY_SCOPE_AGENT);
}
__device__ __forceinline__ float sigm(float x){ return 1.f/(1.f+expf(-x)); }

__global__ __launch_bounds__(TPB, 4) void decoder_persistent(
    const float* __restrict__ xs_h, const float* __restrict__ ys_e,
    const float* __restrict__ xs_mask, const float* __restrict__ ys_mask,
    const float* __restrict__ W_sinit, const float* __restrict__ b_sinit,
    const float* __restrict__ W_keys,
    const float* __restrict__ Wx_cell, const float* __restrict__ bx_cell,
    const float* __restrict__ gx_cell, const float* __restrict__ Wh_cell,
    const float* __restrict__ gh_cell,
    const float* __restrict__ Wx_cond, const float* __restrict__ bx_cond,
    const float* __restrict__ gx_cond, const float* __restrict__ Wh_cond,
    const float* __restrict__ gh_cond,
    const float* __restrict__ Wq, const float* __restrict__ bq,
    const float* __restrict__ V_att, const float* __restrict__ Wo,
    const float* __restrict__ bo, const float* __restrict__ Wy,
    const float* __restrict__ by, const float* __restrict__ Wc,
    const float* __restrict__ bc, const float* __restrict__ Wsm,
    const float* __restrict__ bs,
    float* __restrict__ out, float* __restrict__ ws)
{
    const int w    = blockIdx.x;
    const int tid  = threadIdx.x;
    const int lane = tid & 63, wv = tid >> 6;
    const int i    = w & 7;          // column slice (== XCD under %8 mapping; perf-only)
    const int grp  = w >> 3;         // group 0..31
    const int b0   = grp * 2;        // this group's 2 batch rows

    // ---------------- workspace layout (floats), total ~11.08M = 44.3 MB ----------------
    unsigned* cntg = (unsigned*)ws + (size_t)grp * 16;   // group barrier ctr (64B padded)
    float* AXn  = ws + 1024;                             // [64][64][1536] LN'd x-branch
    float* uhP  = AXn  + (size_t)64*64*1536;             // [256][16][512] WG-private
    float* YWbP = uhP  + (size_t)256*16*512;             // [256][2][64][64] WG-private
    float* PB   = YWbP + (size_t)256*2*64*64;            // [32][18432] per-group block
    float* pb     = PB + (size_t)grp * 18432;
    float* tmpH_  = pb;            // [2][1536]
    float* tmpHC_ = pb + 3072;     // [2][1536]
    float* tmpXC_ = pb + 6144;     // [2][1536]
    float* qb_    = pb + 9216;     // [2][512]
    float* e_     = pb + 10240;    // [2][64][8]
    float* ctx0_  = pb + 11264;    // [2][1024]
    float* ctx_   = pb + 13312;    // [2][1024]
    float* pool_  = pb + 15360;    // [2][1024]
    float* s0_    = pb + 17408;    // [2][512]

    // ---------------- LDS (~125 KB; 1 WG/CU) ----------------
    __shared__ float sal[2][512];    // carry s_t (identical in all 8 WGs)
    __shared__ float sbl[2][512];    // cell-GRU "state"
    __shared__ float al[2][64];      // alpha for head i
    __shared__ float outcl[2][64];   // ctx@Wc slice
    __shared__ float xml[2][64];     // xs_mask rows
    __shared__ float red[8][24];
    __shared__ float red2[24];
    __shared__ float xsl[2*64*128];  // xs_h slice cache: [bb][l][cc], cols i*128..+128 (64 KB)
    __shared__ float arena[13056];   // staging + combine scratch
    float* xv   = arena;             // [2][1024] staging
    float* comb = arena + 2048;      // combine region (<= 4608 floats)

    unsigned gen = 0;
    auto gbar = [&](){
        __syncthreads();             // all WG stores issued (vmcnt drained)
        ++gen;
        if (tid == 0){
            __hip_atomic_fetch_add(cntg, 1u, __ATOMIC_RELEASE, __HIP_MEMORY_SCOPE_AGENT);
            while (__hip_atomic_load(cntg, __ATOMIC_RELAXED, __HIP_MEMORY_SCOPE_AGENT) < 8u*gen)
                __builtin_amdgcn_s_sleep(2);
            __builtin_amdgcn_fence(__ATOMIC_ACQUIRE, "agent");   // single synchronizing acquire
        }
        asm volatile("" ::: "memory");
        __syncthreads();
    };

    auto breduce = [&](float* v, int nv){
        for (int n = 0; n < nv; ++n){
            float x = v[n];
            #pragma unroll
            for (int o = 32; o; o >>= 1) x += __shfl_xor(x, o);
            v[n] = x;
        }
        if (lane == 0) for (int n = 0; n < nv; ++n) red[wv][n] = v[n];
        __syncthreads();
        if (tid < nv){ float s = 0.f; for (int q = 0; q < 8; ++q) s += red[q][tid]; red2[tid] = s; }
        __syncthreads();
        for (int n = 0; n < nv; ++n) v[n] = red2[n];
    };

    // dual-matrix sliced GEMV for 2 batch rows, 256 output cols, K-split 8.
    auto gemv2 = [&](const float* Wa, int lda, int ca,
                     const float* Wb, int ldb, int cb, int CGA,
                     const float* x0, const float* x1, int K)->float{
        int cg = tid & 63, kq = tid >> 6;
        const float* W; int ld, col;
        if (cg < CGA){ W = Wa; ld = lda; col = ca + 4*cg; }
        else         { W = Wb; ld = ldb; col = cb + 4*(cg - CGA); }
        int Kq = K >> 3;
        const float* wp = W + (size_t)(kq*Kq)*ld + col;
        const float* xa = x0 + kq*Kq;
        const float* xb = x1 + kq*Kq;
        float a0=0,a1=0,a2=0,a3=0, c0=0,c1=0,c2=0,c3=0;
        for (int kk = 0; kk < Kq; kk += 8){
            float4 wr[8];
            #pragma unroll
            for (int u = 0; u < 8; ++u) wr[u] = *(const float4*)(wp + (size_t)(kk+u)*ld);
            #pragma unroll
            for (int u = 0; u < 8; ++u){
                float xA = xa[kk+u], xB = xb[kk+u];
                a0 = fmaf(xA, wr[u].x, a0); a1 = fmaf(xA, wr[u].y, a1);
                a2 = fmaf(xA, wr[u].z, a2); a3 = fmaf(xA, wr[u].w, a3);
                c0 = fmaf(xB, wr[u].x, c0); c1 = fmaf(xB, wr[u].y, c1);
                c2 = fmaf(xB, wr[u].z, c2); c3 = fmaf(xB, wr[u].w, c3);
            }
        }
        float* cp = comb + tid*9;
        cp[0]=a0; cp[1]=a1; cp[2]=a2; cp[3]=a3;
        cp[4]=c0; cp[5]=c1; cp[6]=c2; cp[7]=c3;
        __syncthreads();
        int bb = tid >> 8, c = tid & 255, cgq = c >> 2, j = c & 3;
        float s = 0.f;
        #pragma unroll
        for (int q = 0; q < 8; ++q) s += comb[(q*64 + cgq)*9 + bb*4 + j];
        __syncthreads();
        return s;
    };

    // ======================= precompute =======================
    if (tid < 128) xml[tid>>6][tid&63] = xs_mask[(size_t)(b0 + (tid>>6))*64 + (tid&63)];
    // xs_h slice cache: cols [i*128, i*128+128) for both batch rows, all 64 l.
    for (int k = tid; k < 16384; k += TPB){
        int bb = k >> 13, rem = k & 8191, l = rem >> 7, cc = rem & 127;
        xsl[k] = xs_h[((size_t)((b0+bb)*64 + l))*1024 + i*128 + cc];
    }
    __syncthreads();

    // ---- uh (private): 16 jobs (2b x 8 l), 512 cols, K=1024; W_keys read once ----
    {
        int c4 = tid & 127, kq = tid >> 7;           // 4 kq x 256 k
        unsigned base[16];
        #pragma unroll
        for (int j = 0; j < 16; ++j){
            int bb = j >> 3, l = i*8 + (j & 7);
            base[j] = (unsigned)(((b0+bb)*64 + l)*1024 + kq*256);
        }
        const float* wp = W_keys + (size_t)(kq*256)*512 + 4*c4;
        float4 acc[16];
        #pragma unroll
        for (int j = 0; j < 16; ++j) acc[j] = make_float4(0.f,0.f,0.f,0.f);
        for (int kk = 0; kk < 256; ++kk){
            float4 wr = *(const float4*)(wp + (size_t)kk*512);
            #pragma unroll
            for (int j = 0; j < 16; ++j){
                float xr = xs_h[base[j] + kk];
                acc[j].x = fmaf(xr, wr.x, acc[j].x); acc[j].y = fmaf(xr, wr.y, acc[j].y);
                acc[j].z = fmaf(xr, wr.z, acc[j].z); acc[j].w = fmaf(xr, wr.w, acc[j].w);
            }
        }
        for (int r = 0; r < 16; ++r){
            float* cp = arena + tid*5;
            cp[0]=acc[r].x; cp[1]=acc[r].y; cp[2]=acc[r].z; cp[3]=acc[r].w;
            __syncthreads();
            int c = tid; float s = 0.f;
            #pragma unroll
            for (int q = 0; q < 4; ++q) s += arena[(q*128 + (c>>2))*5 + (c&3)];
            uhP[((size_t)w*16 + r)*512 + c] = s;
            __syncthreads();
        }
    }

    // ---- AXn (published to group): 16 rows (2b x 8 t), LN(ys_e@Wx_cell)*gx+bx ----
    // TWO-PASS LN variance (round-3 lesson).
    for (int g = 0; g < 3; ++g){
        int c4 = tid & 127, kq = tid >> 7;           // 4 kq x 128 k
        unsigned base[16];
        #pragma unroll
        for (int j = 0; j < 16; ++j){
            int bb = j >> 3, t = i*8 + (j & 7);
            base[j] = (unsigned)(((b0+bb)*64 + t)*512 + kq*128);
        }
        const float* wp = Wx_cell + (size_t)(kq*128)*1536 + g*512 + 4*c4;
        float4 acc[16];
        #pragma unroll
        for (int j = 0; j < 16; ++j) acc[j] = make_float4(0.f,0.f,0.f,0.f);
        for (int kk = 0; kk < 128; ++kk){
            float4 wr = *(const float4*)(wp + (size_t)kk*1536);
            #pragma unroll
            for (int j = 0; j < 16; ++j){
                float xr = ys_e[base[j] + kk];
                acc[j].x = fmaf(xr, wr.x, acc[j].x); acc[j].y = fmaf(xr, wr.y, acc[j].y);
                acc[j].z = fmaf(xr, wr.z, acc[j].z); acc[j].w = fmaf(xr, wr.w, acc[j].w);
            }
        }
        for (int r = 0; r < 16; ++r){
            float* cp = arena + tid*5;
            cp[0]=acc[r].x; cp[1]=acc[r].y; cp[2]=acc[r].z; cp[3]=acc[r].w;
            __syncthreads();
            int c = tid; float val = 0.f;
            #pragma unroll
            for (int q = 0; q < 4; ++q) val += arena[(q*128 + (c>>2))*5 + (c&3)];
            float s1[1] = { val };
            breduce(s1, 1);
            float mu = s1[0]*(1.f/512.f);
            float d = val - mu;
            float s2[1] = { d*d };
            breduce(s2, 1);
            float rstd = rsqrtf(s2[0]*(1.f/512.f) + 1e-5f);
            int bb = r >> 3, t = i*8 + (r & 7), cg2 = g*512 + c;
            g_st(&AXn[(((size_t)(b0+bb))*64 + t)*1536 + cg2],
                 d*rstd*gx_cell[cg2] + bx_cell[cg2]);
            __syncthreads();
        }
    }

    // ---- YWb (private): 128 rows (2b x 64 t) in 8 chunks, 64-col slice ----
    for (int cc = 0; cc < 8; ++cc){
        int c4 = tid & 15, kq = tid >> 4;            // 32 kq x 16 k
        unsigned base[16];
        #pragma unroll
        for (int r = 0; r < 16; ++r){
            int rg = cc*16 + r, bb = rg >> 6, t = rg & 63;
            base[r] = (unsigned)(((b0+bb)*64 + t)*512 + kq*16);
        }
        const float* wp = Wy + (size_t)(kq*16)*512 + i*64 + 4*c4;
        float4 acc[16];
        #pragma unroll
        for (int r = 0; r < 16; ++r) acc[r] = make_float4(0.f,0.f,0.f,0.f);
        for (int kk = 0; kk < 16; ++kk){
            float4 wr = *(const float4*)(wp + (size_t)kk*512);
            #pragma unroll
            for (int r = 0; r < 16; ++r){
                float xr = ys_e[base[r] + kk];
                acc[r].x = fmaf(xr, wr.x, acc[r].x); acc[r].y = fmaf(xr, wr.y, acc[r].y);
                acc[r].z = fmaf(xr, wr.z, acc[r].z); acc[r].w = fmaf(xr, wr.w, acc[r].w);
            }
        }
        for (int r = 0; r < 16; ++r){
            float* cp = arena + tid*5;
            cp[0]=acc[r].x; cp[1]=acc[r].y; cp[2]=acc[r].z; cp[3]=acc[r].w;
            __syncthreads();
            if (tid < 64){
                int c = tid; float s = 0.f;
                #pragma unroll
                for (int q = 0; q < 32; ++q) s += arena[(q*16 + (c>>2))*5 + (c&3)];
                int rg = cc*16 + r, bb = rg >> 6, t = rg & 63;
                YWbP[(((size_t)w*2 + bb)*64 + t)*64 + c] = s + by[i*64 + c];
            }
            __syncthreads();
        }
    }

    // ---- pooled slice (from LDS cache; bit-identical values/order) ----
    if (tid < 256){
        int bb = tid >> 7, c = tid & 127;
        float msum = 0.f;
        for (int l = 0; l < 64; ++l) msum += xml[bb][l];
        float a = 0.f;
        for (int l = 0; l < 64; ++l)
            a += xsl[(bb*64 + l)*128 + c] * xml[bb][l];
        g_st(&pool_[bb*1024 + i*128 + c], a / msum);
    }
    gbar();   // publish AXn + pooled

    // ---- s0 = tanh(pooled @ W_sinit + b) ----
    for (int k = tid; k < 2048; k += TPB) xv[k] = g_ld(&pool_[k]);
    __syncthreads();
    {
        int c4 = tid & 15, kq = tid >> 4;            // 32 kq x 32 k
        const float* wp = W_sinit + (size_t)(kq*32)*512 + i*64 + 4*c4;
        float4 A = make_float4(0.f,0.f,0.f,0.f), Bv = make_float4(0.f,0.f,0.f,0.f);
        for (int kk = 0; kk < 32; ++kk){
            float4 wr = *(const float4*)(wp + (size_t)kk*512);
            float xA = xv[kq*32 + kk], xB = xv[1024 + kq*32 + kk];
            A.x = fmaf(xA, wr.x, A.x); A.y = fmaf(xA, wr.y, A.y);
            A.z = fmaf(xA, wr.z, A.z); A.w = fmaf(xA, wr.w, A.w);
            Bv.x = fmaf(xB, wr.x, Bv.x); Bv.y = fmaf(xB, wr.y, Bv.y);
            Bv.z = fmaf(xB, wr.z, Bv.z); Bv.w = fmaf(xB, wr.w, Bv.w);
        }
        float* cp = comb + tid*9;
        cp[0]=A.x; cp[1]=A.y; cp[2]=A.z; cp[3]=A.w;
        cp[4]=Bv.x; cp[5]=Bv.y; cp[6]=Bv.z; cp[7]=Bv.w;
        __syncthreads();
        if (tid < 128){
            int bb = tid >> 6, c = tid & 63; float s = 0.f;
            #pragma unroll
            for (int q = 0; q < 32; ++q) s += comb[(q*16 + (c>>2))*9 + bb*4 + (c&3)];
            g_st(&s0_[bb*512 + i*64 + c], tanhf(s + b_sinit[i*64 + c]));
        }
        __syncthreads();
    }
    gbar();
    sal[0][tid] = g_ld(&s0_[tid]);
    sal[1][tid] = g_ld(&s0_[512 + tid]);
    __syncthreads();

    // ---- tmpH for t=0 ----
    {
        float r0 = gemv2(Wsm, 512, i*64, Wh_cell, 1536, i*192, 16,
                         &sal[0][0], &sal[1][0], 512);
        int bb = tid >> 8, c = tid & 255;
        if (c >= 64) g_st(&tmpH_[bb*1536 + i*192 + (c - 64)], r0);
    }
    gbar();

    // ======================= sequential scan =======================
    for (int t = 0; t < 64; ++t){
        float ymr[2] = { ys_mask[(size_t)b0*64 + t], ys_mask[(size_t)(b0+1)*64 + t] };

        // ---- phase A: cell-GRU (redundant, two-pass LN) + qb/tmpHC slice ----
        {
            float th[2][3], ax[2][3], st[6];
            #pragma unroll
            for (int bb = 0; bb < 2; ++bb)
                #pragma unroll
                for (int g = 0; g < 3; ++g){
                    th[bb][g] = g_ld(&tmpH_[bb*1536 + g*512 + tid]);
                    ax[bb][g] = g_ld(&AXn[(((size_t)(b0+bb))*64 + t)*1536 + g*512 + tid]);
                    st[bb*3+g] = th[bb][g];
                }
            breduce(st, 6);
            float dv[2][3], st2[6];
            #pragma unroll
            for (int bb = 0; bb < 2; ++bb)
                #pragma unroll
                for (int g = 0; g < 3; ++g){
                    float mu = st[bb*3+g]*(1.f/512.f);
                    dv[bb][g] = th[bb][g] - mu;
                    st2[bb*3+g] = dv[bb][g]*dv[bb][g];
                }
            breduce(st2, 6);
            #pragma unroll
            for (int bb = 0; bb < 2; ++bb){
                float ah[3];
                #pragma unroll
                for (int g = 0; g < 3; ++g){
                    float var = st2[bb*3+g]*(1.f/512.f);
                    ah[g] = dv[bb][g]*rsqrtf(var + 1e-5f)*gh_cell[g*512 + tid];
                }
                float h  = sal[bb][tid];
                float r  = sigm(ax[bb][0] + ah[0]);
                float z  = sigm(ax[bb][1] + ah[1]);
                float hc = tanhf(ax[bb][2] + r*ah[2]);
                float hn = (1.f - z)*h + z*hc;
                sbl[bb][tid] = ymr[bb]*hn + (1.f - ymr[bb])*h;
            }
        }
        __syncthreads();
        {
            float ra = gemv2(Wq, 512, i*64, Wh_cond, 1536, i*192, 16,
                             &sbl[0][0], &sbl[1][0], 512);
            int bb = tid >> 8, c = tid & 255;
            if (c < 64){ int col = i*64 + c; g_st(&qb_[bb*512 + col], ra + bq[col]); }
            else g_st(&tmpHC_[bb*1536 + i*192 + (c - 64)], ra);
        }
        gbar();  // A

        // ---- phase B: attention scores for my 16 (b,l) jobs ----
        for (int k = tid; k < 1024; k += TPB) xv[k] = g_ld(&qb_[k]);
        __syncthreads();
        for (int jj = wv; jj < 16; jj += 8){
            int bb = jj >> 3, l = i*8 + (jj & 7);
            float acc[8] = {0.f,0.f,0.f,0.f,0.f,0.f,0.f,0.f};
            #pragma unroll
            for (int u = 0; u < 8; ++u){
                int d = u*64 + lane;
                float hid = tanhf(uhP[((size_t)w*16 + jj)*512 + d] + xv[bb*512 + d]);
                float4 va = *(const float4*)&V_att[(size_t)d*8];
                float4 vb = *(const float4*)&V_att[(size_t)d*8 + 4];
                acc[0] = fmaf(hid, va.x, acc[0]); acc[1] = fmaf(hid, va.y, acc[1]);
                acc[2] = fmaf(hid, va.z, acc[2]); acc[3] = fmaf(hid, va.w, acc[3]);
                acc[4] = fmaf(hid, vb.x, acc[4]); acc[5] = fmaf(hid, vb.y, acc[5]);
                acc[6] = fmaf(hid, vb.z, acc[6]); acc[7] = fmaf(hid, vb.w, acc[7]);
            }
            #pragma unroll
            for (int h = 0; h < 8; ++h)
                #pragma unroll
                for (int o = 32; o; o >>= 1) acc[h] += __shfl_xor(acc[h], o);
            if (lane == 0){
                float mk = xml[bb][l];
                #pragma unroll
                for (int h = 0; h < 8; ++h)
                    g_st(&e_[((size_t)bb*64 + l)*8 + h], (mk > 0.f) ? acc[h] : -1e9f);
            }
        }
        gbar();  // B

        // ---- phase C: softmax (head i) + ctx0 slice (xs_h from LDS cache) ----
        if (wv < 2){
            int bb = wv;
            float v = g_ld(&e_[((size_t)bb*64 + lane)*8 + i]);
            float mx = v;
            #pragma unroll
            for (int o = 32; o; o >>= 1) mx = fmaxf(mx, __shfl_xor(mx, o));
            float ex = expf(v - mx);
            float ss = ex;
            #pragma unroll
            for (int o = 32; o; o >>= 1) ss += __shfl_xor(ss, o);
            al[bb][lane] = ex / ss;
        }
        __syncthreads();
        {
            int kq = tid >> 6, job = tid & 63, bb = job >> 5, cg = job & 31;
            float4 a4 = make_float4(0.f,0.f,0.f,0.f);
            #pragma unroll
            for (int u = 0; u < 8; ++u){
                int l = kq*8 + u;
                float a = al[bb][l];
                float4 xw = *(const float4*)&xsl[((bb*64 + l) << 7) + 4*cg];
                a4.x = fmaf(a, xw.x, a4.x); a4.y = fmaf(a, xw.y, a4.y);
                a4.z = fmaf(a, xw.z, a4.z); a4.w = fmaf(a, xw.w, a4.w);
            }
            float* cp = comb + tid*5;
            cp[0]=a4.x; cp[1]=a4.y; cp[2]=a4.z; cp[3]=a4.w;
            __syncthreads();
            if (tid < 256){
                int bb2 = tid >> 7, c = tid & 127; float s = 0.f;
                #pragma unroll
                for (int q = 0; q < 8; ++q) s += comb[(q*64 + bb2*32 + (c>>2))*5 + (c&3)];
                g_st(&ctx0_[bb2*1024 + i*128 + c], s);
            }
            __syncthreads();
        }
        gbar();  // C

        // ---- phase D: ctx = (ctx0 @ Wo + bo) * ym  (direct Wo, K-split 16) ----
        for (int k = tid; k < 2048; k += TPB) xv[k] = g_ld(&ctx0_[k]);
        __syncthreads();
        {
            int kq = tid >> 5, cg = tid & 31;        // 16 kq x 64 k, 32 cg x 4 cols
            int c0 = i*128 + 4*cg;
            const float* wp = Wo + (size_t)(kq*64)*1024 + c0;
            const float* xa = xv + kq*64;
            const float* xb = xv + 1024 + kq*64;
            float a0=0,a1=0,a2=0,a3=0, d0=0,d1=0,d2=0,d3=0;
            for (int kk = 0; kk < 64; kk += 8){
                float4 wr[8];
                #pragma unroll
                for (int u = 0; u < 8; ++u) wr[u] = *(const float4*)(wp + (size_t)(kk+u)*1024);
                #pragma unroll
                for (int u = 0; u < 8; ++u){
                    float xA = xa[kk+u], xB = xb[kk+u];
                    a0 = fmaf(xA, wr[u].x, a0); a1 = fmaf(xA, wr[u].y, a1);
                    a2 = fmaf(xA, wr[u].z, a2); a3 = fmaf(xA, wr[u].w, a3);
                    d0 = fmaf(xB, wr[u].x, d0); d1 = fmaf(xB, wr[u].y, d1);
                    d2 = fmaf(xB, wr[u].z, d2); d3 = fmaf(xB, wr[u].w, d3);
                }
            }
            float* cp = comb + tid*9;
            cp[0]=a0; cp[1]=a1; cp[2]=a2; cp[3]=a3;
            cp[4]=d0; cp[5]=d1; cp[6]=d2; cp[7]=d3;
            __syncthreads();
            if (tid < 256){
                int bb2 = tid >> 7, c = tid & 127; float s = 0.f;
                #pragma unroll
                for (int q = 0; q < 16; ++q) s += comb[(q*32 + (c>>2))*9 + bb2*4 + (c&3)];
                float ym2 = bb2 ? ymr[1] : ymr[0];
                g_st(&ctx_[bb2*1024 + i*128 + c], (s + bo[i*128 + c]) * ym2);
            }
            __syncthreads();
        }
        gbar();  // D

        // ---- phase E: tmpXC (Wx_cond) + outc (Wc) from ctx ----
        for (int k = tid; k < 2048; k += TPB) xv[k] = g_ld(&ctx_[k]);
        __syncthreads();
        {
            float re = gemv2(Wx_cond, 1536, i*192, Wc, 512, i*64, 48,
                             &xv[0], &xv[1024], 1024);
            int bb = tid >> 8, c = tid & 255;
            if (c < 192){
                g_st(&tmpXC_[bb*1536 + i*192 + c], re);
            } else {
                outcl[bb][c - 192] = re;
            }
        }
        gbar();  // E

        // ---- phase F: cond-GRU (redundant, two-pass LN) + out + tmpH(t+1) ----
        {
            float tx[2][3], th[2][3], st[12];
            #pragma unroll
            for (int bb = 0; bb < 2; ++bb)
                #pragma unroll
                for (int g = 0; g < 3; ++g){
                    tx[bb][g] = g_ld(&tmpXC_[bb*1536 + g*512 + tid]);
                    th[bb][g] = g_ld(&tmpHC_[bb*1536 + g*512 + tid]);
                    st[bb*3+g]     = tx[bb][g];
                    st[6 + bb*3+g] = th[bb][g];
                }
            breduce(st, 12);
            float dx[2][3], dh[2][3], st2[12];
            #pragma unroll
            for (int bb = 0; bb < 2; ++bb)
                #pragma unroll
                for (int g = 0; g < 3; ++g){
                    float mux = st[bb*3+g]*(1.f/512.f);
                    float muh = st[6 + bb*3+g]*(1.f/512.f);
                    dx[bb][g] = tx[bb][g] - mux;
                    dh[bb][g] = th[bb][g] - muh;
                    st2[bb*3+g]     = dx[bb][g]*dx[bb][g];
                    st2[6 + bb*3+g] = dh[bb][g]*dh[bb][g];
                }
            breduce(st2, 12);
            float snew[2];
            #pragma unroll
            for (int bb = 0; bb < 2; ++bb){
                float axc[3], ahc[3];
                #pragma unroll
                for (int g = 0; g < 3; ++g){
                    int c2 = g*512 + tid;
                    float vax = st2[bb*3+g]*(1.f/512.f);
                    float vah = st2[6 + bb*3+g]*(1.f/512.f);
                    axc[g] = dx[bb][g]*rsqrtf(vax + 1e-5f)*gx_cond[c2] + bx_cond[c2];
                    ahc[g] = dh[bb][g]*rsqrtf(vah + 1e-5f)*gh_cond[c2];
                }
                float h  = sbl[bb][tid];
                float r  = sigm(axc[0] + ahc[0]);
                float z  = sigm(axc[1] + ahc[1]);
                float hc = tanhf(axc[2] + r*ahc[2]);
                float hn = (1.f - z)*h + z*hc;
                snew[bb] = ymr[bb]*hn + (1.f - ymr[bb])*h;
            }
            sal[0][tid] = snew[0];
            sal[1][tid] = snew[1];
        }
        __syncthreads();
        {
            float rf = gemv2(Wsm, 512, i*64, Wh_cell, 1536, i*192, 16,
                             &sal[0][0], &sal[1][0], 512);
            int bb = tid >> 8, c = tid & 255;
            if (c < 64){
                int col = i*64 + c;
                float ymf = bb ? ymr[1] : ymr[0];
                float v = rf + YWbP[(((size_t)w*2 + bb)*64 + t)*64 + c]
                        + outcl[bb][c] + bc[col] + bs[col];
                out[(((size_t)(b0+bb))*64 + t)*512 + col] = tanhf(v)*ymf;
            } else {
                g_st(&tmpH_[bb*1536 + i*192 + (c - 64)], rf);
            }
        }
        gbar();  // F
    }
}

// ---------------------------------------------------------------------------
extern "C" void kernel_launch(void* const* d_in, const int* in_sizes, int n_in,
                              void* d_out, int out_size, void* d_ws, size_t ws_size,
                              hipStream_t stream)
{
    // re-zero barrier counters on every graph replay
    hipMemsetAsync(d_ws, 0, 4096, stream);

    decoder_persistent<<<dim3(NWG), dim3(TPB), 0, stream>>>(
        (const float*)d_in[0],  (const float*)d_in[1],  (const float*)d_in[2],
        (const float*)d_in[3],  (const float*)d_in[4],  (const float*)d_in[5],
        (const float*)d_in[6],  (const float*)d_in[7],  (const float*)d_in[8],
        (const float*)d_in[9],  (const float*)d_in[10], (const float*)d_in[11],
        (const float*)d_in[12], (const float*)d_in[13], (const float*)d_in[14],
        (const float*)d_in[15], (const float*)d_in[16], (const float*)d_in[17],
        (const float*)d_in[18], (const float*)d_in[19], (const float*)d_in[20],
        (const float*)d_in[21], (const float*)d_in[22], (const float*)d_in[23],
        (const float*)d_in[24], (const float*)d_in[25], (const float*)d_in[26],
        (const float*)d_in[27],
        (float*)d_out, (float*)d_ws);
}